// Round 3
// baseline (6528.722 us; speedup 1.0000x reference)
//
#include <hip/hip_runtime.h>
#include <hip/hip_bf16.h>

#define B   128
#define NA  8
#define AD  16
#define DM  512
#define DI  1024
#define DS  32
#define DC  4
#define DR  32
#define NB  4
#define OD  128

typedef __hip_bfloat16 bf16;
typedef unsigned int uint32;
typedef unsigned short ushort16;

__device__ __forceinline__ float sigmoidf_(float x){ return 1.0f/(1.0f+__expf(-x)); }
__device__ __forceinline__ float softplusf_(float x){ return fmaxf(x,0.0f)+log1pf(__expf(-fabsf(x))); }
__device__ __forceinline__ float lo2f(uint32 u){ return __uint_as_float(u<<16); }
__device__ __forceinline__ float hi2f(uint32 u){ return __uint_as_float(u & 0xffff0000u); }
__device__ __forceinline__ uint32 packbf2(float a, float b){
    bf16 ha = __float2bfloat16(a), hb = __float2bfloat16(b);
    ushort16 sa = *reinterpret_cast<ushort16*>(&ha);
    ushort16 sb = *reinterpret_cast<ushort16*>(&hb);
    return (uint32)sa | ((uint32)sb << 16);
}
__device__ __forceinline__ ushort16 f2us(float a){
    bf16 ha = __float2bfloat16(a);
    return *reinterpret_cast<ushort16*>(&ha);
}

// ---------------- init / conversion kernels (unchanged layouts) ----------------

__global__ __launch_bounds__(256) void k_negA(const float* __restrict__ Als,
    const float* __restrict__ Alc, float* __restrict__ negA)
{
    int idx = blockIdx.x*256 + threadIdx.x;   // < 2*NB*DI*DS = 262144
    int bs = idx >> 15;
    int r  = idx & 32767;
    int nb = bs >> 1, st = bs & 1;
    const float* src = (st ? Alc : Als) + (size_t)nb*DI*DS + r;
    negA[idx] = -__expf(*src);
}

__global__ __launch_bounds__(256) void k_ctx(const float* __restrict__ obs_rep,
    const float* __restrict__ obs, const float* __restrict__ Wobs,
    float* __restrict__ ctx)
{
    int ib = blockIdx.x;          // < B*8
    int b = ib >> 3, i = ib & 7;
    __shared__ float orow[OD];
    int tid = threadIdx.x;
    if (tid < OD) orow[tid] = obs[(size_t)(b*NA+i)*OD + tid];
    __syncthreads();
    for (int m = tid; m < DM; m += 256){
        float acc = obs_rep[(size_t)(b*NA+i)*DM + m];
        for (int o = 0; o < OD; o++)
            acc += orow[o]*Wobs[o*DM + m];
        ctx[(size_t)(i*B + b)*DM + m] = acc;
    }
}

// W1b[bs][k][c] bf16, [8][512][2048]
__global__ __launch_bounds__(256) void k_w1(const float* __restrict__ Ws,
    const float* __restrict__ Wc, ushort16* __restrict__ W1b)
{
    int idx = blockIdx.x*256 + threadIdx.x;   // < 8*1048576
    int bs = idx >> 20;
    int r  = idx & 1048575;
    int nb = bs >> 1, st = bs & 1;
    const float* src = (st ? Wc : Ws) + (size_t)nb*1048576 + r;
    W1b[idx] = f2us(*src);
}

// WoU[bs][k][p] = packed pair (cols 2p,2p+1) of out_proj (1024 x 512)
__global__ __launch_bounds__(256) void k_wo(const float* __restrict__ Ws,
    const float* __restrict__ Wc, uint32* __restrict__ WoU)
{
    int idx = blockIdx.x*256 + threadIdx.x;   // < 8*262144
    int bs = idx >> 18;
    int r  = idx & 262143;
    int k  = r >> 8, p = r & 255;
    int nb = bs >> 1, st = bs & 1;
    const float* src = (st ? Wc : Ws) + (size_t)nb*DI*DM + (size_t)k*DM + 2*p;
    WoU[idx] = packbf2(src[0], src[1]);
}

// Wxb[bs][j][k] bf16 — TRANSPOSED x_proj: [8][96][1024]
__global__ __launch_bounds__(256) void k_wx(const float* __restrict__ Ws,
    const float* __restrict__ Wc, ushort16* __restrict__ Wxb)
{
    int idx = blockIdx.x*256 + threadIdx.x;   // < 8*98304
    int bs = idx / 98304;
    int r  = idx % 98304;
    int j  = r >> 10, k = r & 1023;
    int nb = bs >> 1, st = bs & 1;
    const float* src = (st ? Wc : Ws) + (size_t)nb*DI*96 + (size_t)k*96 + j;
    Wxb[idx] = f2us(*src);
}

// Wdtb[bs][r][d] bf16 [8][32][1024]
__global__ __launch_bounds__(256) void k_wdt(const float* __restrict__ Ws,
    const float* __restrict__ Wc, ushort16* __restrict__ Wdtb)
{
    int idx = blockIdx.x*256 + threadIdx.x;   // < 8*32768
    int bs = idx >> 15;
    int r  = idx & 32767;
    int nb = bs >> 1, st = bs & 1;
    const float* src = (st ? Wc : Ws) + (size_t)nb*DR*DI + r;
    Wdtb[idx] = f2us(*src);
}

// ---------------- one-block-per-row persistent kernel (no grid sync) ----------------

struct KP {
    const bf16  *W1b, *Wxb, *Wdtb;
    const uint32 *WoU;
    const float *negA, *ctxG;
    const float *cw_s, *cb_s, *dtb_s, *D_s;
    const float *cw_c, *cb_c, *dtb_c, *D_c;
    const float *ln1, *ln2, *lno, *Whead, *logstd, *eps, *Wemb, *bemb;
    float *out;
    uint32 *convrU, *hG;
};

// 128 blocks (one per batch row) x 1024 threads. Everything per-row lives in
// LDS; only weights (shared, read-only), the conv ring and h-state (both
// block-private) touch global memory. Zero inter-block communication =>
// zero device fences => L2 stays warm with the weight stream.
__global__ __launch_bounds__(1024, 4) void k_row(KP P)
{
    const int row = blockIdx.x;
    const int t = threadIdx.x;
    const int lane = t & 63, wid = t >> 6;

    __shared__ float xL[512];          // residual stream
    __shared__ float yoL[512];         // last gemm2 output (init 0)
    alignas(16) __shared__ float ulnL[512];
    __shared__ float xzL[2048];        // gemm1 out: [0..1023]=x, [1024..2047]=z
    __shared__ float xcL[1024];        // conv+silu
    __shared__ float szL[1024];        // silu(z)
    __shared__ float partx[768];
    __shared__ float rowS[96];
    alignas(16) __shared__ float yzL[1024];
    __shared__ float red2[4][512];
    __shared__ float redH[512];
    __shared__ float wps[8], wpq[8], ms2[2];
    __shared__ float actv[AD], lpterm[AD];
    __shared__ float occpad[11264];    // ~44KB pad -> >80KB LDS -> 1 block/CU
    if (P.out == (float*)P.convrU) occpad[t] = 0.f;   // never true; keeps pad alive

    if (t < 512){ xL[t] = P.bemb[t]; yoL[t] = 0.f; }
    __syncthreads();

    #pragma unroll 1
    for (int i = 0; i < NA; i++){
        #pragma unroll 1
        for (int bs = 0; bs < 8; bs++){
            const int nb = bs >> 1, st = bs & 1;
            const float* cw   = (st ? P.cw_c : P.cw_s) + (size_t)nb*DC*DI;
            const float* cb   = (st ? P.cb_c : P.cb_s) + (size_t)nb*DI;
            const float* lns  = (st ? P.ln2  : P.ln1 ) + (size_t)nb*DM;
            const float* dtbp = (st ? P.dtb_c : P.dtb_s) + (size_t)nb*DI;
            const float* Dpp  = (st ? P.D_c   : P.D_s  ) + (size_t)nb*DI;

            // ---- fold residual + LN ----
            float vv = 0.f;
            if (t < 512){
                vv = xL[t] + yoL[t];
                xL[t] = vv;
                float sv = vv, qv = vv*vv;
                #pragma unroll
                for (int off = 32; off > 0; off >>= 1){
                    sv += __shfl_down(sv, off);
                    qv += __shfl_down(qv, off);
                }
                if (lane == 0){ wps[wid] = sv; wpq[wid] = qv; }
            }
            __syncthreads();
            if (t == 0){
                float S = 0.f, Q = 0.f;
                #pragma unroll
                for (int w2 = 0; w2 < 8; w2++){ S += wps[w2]; Q += wpq[w2]; }
                float m = S*(1.0f/DM);
                float var = Q*(1.0f/DM) - m*m;
                ms2[0] = m; ms2[1] = rsqrtf(var + 1e-5f);
            }
            __syncthreads();
            if (t < 512){
                float u = (vv - ms2[0])*ms2[1]*lns[t];
                if (st) u += P.ctxG[((size_t)i*B + row)*DM + t];
                ulnL[t] = u;
            }
            __syncthreads();

            // ---- gemm1: thread t owns cols (2t,2t+1) of 2048; k=0..511 ----
            {
                const uint32* w1 = (const uint32*)P.W1b + ((size_t)bs << 19) + t;
                float a0 = 0.f, a1 = 0.f;
                #pragma unroll 2
                for (int k4 = 0; k4 < 512; k4 += 4){
                    float4 u4 = *(const float4*)&ulnL[k4];
                    uint32 w0 = w1[(size_t)(k4+0) << 10];
                    uint32 wA = w1[(size_t)(k4+1) << 10];
                    uint32 wB = w1[(size_t)(k4+2) << 10];
                    uint32 wC = w1[(size_t)(k4+3) << 10];
                    a0 += u4.x*lo2f(w0); a1 += u4.x*hi2f(w0);
                    a0 += u4.y*lo2f(wA); a1 += u4.y*hi2f(wA);
                    a0 += u4.z*lo2f(wB); a1 += u4.z*hi2f(wB);
                    a0 += u4.w*lo2f(wC); a1 += u4.w*hi2f(wC);
                }
                xzL[2*t]   = a0;
                xzL[2*t+1] = a1;
            }
            __syncthreads();

            // ---- conv ring + silu -> xc (t<512) ; silu(z) (t>=512) ----
            if (t < 512){
                int p = t, d0 = 2*t;
                float xz0 = xzL[d0], xz1 = xzL[d0+1];
                uint32* ring = P.convrU + ((size_t)bs << 18);   // [4][128][512]
                size_t rb = (size_t)row*512 + p;
                ring[((size_t)(i&3))*65536 + rb] = packbf2(xz0, xz1);
                float s0 = cb[d0]   + cw[3*DI + d0]  *xz0;
                float s1 = cb[d0+1] + cw[3*DI + d0+1]*xz1;
                if (i >= 1){ uint32 uu = ring[((size_t)((i-1)&3))*65536 + rb];
                    s0 += cw[2*DI + d0]*lo2f(uu); s1 += cw[2*DI + d0+1]*hi2f(uu); }
                if (i >= 2){ uint32 uu = ring[((size_t)((i-2)&3))*65536 + rb];
                    s0 += cw[1*DI + d0]*lo2f(uu); s1 += cw[1*DI + d0+1]*hi2f(uu); }
                if (i >= 3){ uint32 uu = ring[((size_t)((i-3)&3))*65536 + rb];
                    s0 += cw[0*DI + d0]*lo2f(uu); s1 += cw[0*DI + d0+1]*hi2f(uu); }
                xcL[d0]   = s0*sigmoidf_(s0);
                xcL[d0+1] = s1*sigmoidf_(s1);
            } else {
                int c = 2*(t - 512);
                float z0 = xzL[1024 + c], z1 = xzL[1024 + c + 1];
                szL[c]   = z0*sigmoidf_(z0);
                szL[c+1] = z1*sigmoidf_(z1);
            }
            __syncthreads();

            // ---- xproj: 96 outputs x 8 k-slices of 128 ----
            if (t < 768){
                int j = t >> 3, sl = t & 7;
                const uint4* wx4 = (const uint4*)(P.Wxb + (size_t)bs*98304
                                                  + (size_t)j*1024 + sl*128);
                const float* xr = &xcL[sl*128];
                float acc = 0.f;
                #pragma unroll 4
                for (int ii = 0; ii < 16; ii++){
                    uint4 q4 = wx4[ii];
                    int kk = 8*ii;
                    acc += xr[kk+0]*lo2f(q4.x) + xr[kk+1]*hi2f(q4.x)
                         + xr[kk+2]*lo2f(q4.y) + xr[kk+3]*hi2f(q4.y)
                         + xr[kk+4]*lo2f(q4.z) + xr[kk+5]*hi2f(q4.z)
                         + xr[kk+6]*lo2f(q4.w) + xr[kk+7]*hi2f(q4.w);
                }
                partx[t] = acc;
            }
            __syncthreads();
            if (t < 96){
                float sa = partx[t*8];
                #pragma unroll
                for (int q = 1; q < 8; q++) sa += partx[t*8 + q];
                rowS[t] = sa;
            }
            __syncthreads();

            // ---- dt + SSM scan + y (thread t owns channel d=t) ----
            {
                int d = t;
                float dp = dtbp[d];
                const ushort16* wdt = (const ushort16*)P.Wdtb + ((size_t)bs << 15) + d;
                #pragma unroll 8
                for (int r = 0; r < DR; r++)
                    dp += rowS[r]*__uint_as_float(((uint32)wdt[(size_t)r << 10]) << 16);
                float delta = softplusf_(dp);
                float xcv = xcL[d];
                float dxc = delta*xcv;
                const float4* nap = (const float4*)(P.negA + ((size_t)bs << 15) + (size_t)d*DS);
                uint4* hp = (uint4*)(P.hG + (((size_t)bs*B + row)*DI + d)*16);
                float y = 0.f;
                const int first = (i == 0);
                #pragma unroll
                for (int qq = 0; qq < 4; qq++){
                    uint4 hu = first ? make_uint4(0u,0u,0u,0u) : hp[qq];
                    float4 na0 = nap[2*qq], na1 = nap[2*qq+1];
                    int s0 = 8*qq;
                    float h0 = lo2f(hu.x), h1 = hi2f(hu.x);
                    float h2 = lo2f(hu.y), h3 = hi2f(hu.y);
                    float h4 = lo2f(hu.z), h5 = hi2f(hu.z);
                    float h6 = lo2f(hu.w), h7 = hi2f(hu.w);
                    h0 = __expf(delta*na0.x)*h0 + dxc*rowS[DR+s0+0];
                    h1 = __expf(delta*na0.y)*h1 + dxc*rowS[DR+s0+1];
                    h2 = __expf(delta*na0.z)*h2 + dxc*rowS[DR+s0+2];
                    h3 = __expf(delta*na0.w)*h3 + dxc*rowS[DR+s0+3];
                    h4 = __expf(delta*na1.x)*h4 + dxc*rowS[DR+s0+4];
                    h5 = __expf(delta*na1.y)*h5 + dxc*rowS[DR+s0+5];
                    h6 = __expf(delta*na1.z)*h6 + dxc*rowS[DR+s0+6];
                    h7 = __expf(delta*na1.w)*h7 + dxc*rowS[DR+s0+7];
                    y += h0*rowS[DR+DS+s0+0] + h1*rowS[DR+DS+s0+1]
                       + h2*rowS[DR+DS+s0+2] + h3*rowS[DR+DS+s0+3]
                       + h4*rowS[DR+DS+s0+4] + h5*rowS[DR+DS+s0+5]
                       + h6*rowS[DR+DS+s0+6] + h7*rowS[DR+DS+s0+7];
                    hu.x = packbf2(h0,h1); hu.y = packbf2(h2,h3);
                    hu.z = packbf2(h4,h5); hu.w = packbf2(h6,h7);
                    hp[qq] = hu;
                }
                y += Dpp[d]*xcv;
                yzL[d] = y*szL[d];
            }
            __syncthreads();

            // ---- gemm2: pair p=t&255 (cols 2p,2p+1), k-slice s=t>>8 (256 k) ----
            {
                int p = t & 255, sl = t >> 8;
                const uint32* wo = P.WoU + ((size_t)bs << 18) + p;
                int k0 = sl*256;
                float b0 = 0.f, b1 = 0.f;
                #pragma unroll 2
                for (int k4 = 0; k4 < 256; k4 += 4){
                    float4 y4 = *(const float4*)&yzL[k0 + k4];
                    uint32 w0 = wo[(size_t)(k0+k4+0) << 8];
                    uint32 wA = wo[(size_t)(k0+k4+1) << 8];
                    uint32 wB = wo[(size_t)(k0+k4+2) << 8];
                    uint32 wC = wo[(size_t)(k0+k4+3) << 8];
                    b0 += y4.x*lo2f(w0); b1 += y4.x*hi2f(w0);
                    b0 += y4.y*lo2f(wA); b1 += y4.y*hi2f(wA);
                    b0 += y4.z*lo2f(wB); b1 += y4.z*hi2f(wB);
                    b0 += y4.w*lo2f(wC); b1 += y4.w*hi2f(wC);
                }
                red2[sl][2*p]   = b0;
                red2[sl][2*p+1] = b1;
            }
            __syncthreads();
            if (t < 512)
                yoL[t] = red2[0][t] + red2[1][t] + red2[2][t] + red2[3][t];
            __syncthreads();
        } // bs

        // ---- head for this row, agent i ----
        {
            float vv = 0.f;
            if (t < 512){
                vv = xL[t] + yoL[t];
                float sv = vv, qv = vv*vv;
                #pragma unroll
                for (int off = 32; off > 0; off >>= 1){
                    sv += __shfl_down(sv, off);
                    qv += __shfl_down(qv, off);
                }
                if (lane == 0){ wps[wid] = sv; wpq[wid] = qv; }
            }
            __syncthreads();
            if (t == 0){
                float S = 0.f, Q = 0.f;
                #pragma unroll
                for (int w2 = 0; w2 < 8; w2++){ S += wps[w2]; Q += wpq[w2]; }
                float m = S*(1.0f/DM);
                float var = Q*(1.0f/DM) - m*m;
                ms2[0] = m; ms2[1] = rsqrtf(var + 1e-5f);
            }
            __syncthreads();
            if (t < 512) ulnL[t] = (vv - ms2[0])*ms2[1]*P.lno[t];
            __syncthreads();
            if (t < 512){
                int ks = t >> 4, j = t & 15;
                float acc = 0.f;
                int k0 = ks*16;
                #pragma unroll
                for (int k = k0; k < k0 + 16; k++)
                    acc += ulnL[k]*P.Whead[k*AD + j];
                redH[t] = acc;
            }
            __syncthreads();
            if (t < AD){
                int j = t;
                float mean = 0.f;
                #pragma unroll
                for (int ks = 0; ks < 32; ks++) mean += redH[ks*16 + j];
                float stdj = softplusf_(P.logstd[j]);
                float e = P.eps[((size_t)row*NA + i)*AD + j];
                float raw = mean + stdj*e;
                float act = tanhf(raw);
                P.out[((size_t)row*NA + i)*AD + j] = act;                                  // acts
                P.out[(size_t)NA*B*AD + (size_t)B*NA + ((size_t)row*NA + i)*AD + j] = raw; // raws
                actv[j] = act;
                lpterm[j] = -0.5f*e*e - logf(stdj)
                            - 2.0f*(0.69314718f - raw - softplusf_(-2.0f*raw));
            }
            __syncthreads();
            if (t == 0){
                float lp = 0.f;
                #pragma unroll
                for (int j = 0; j < AD; j++) lp += lpterm[j];
                lp -= 0.5f*AD*1.8378770664f;
                P.out[(size_t)NA*B*AD + (size_t)row*NA + i] = lp;                          // logs
            }
            if (t < 512){
                float v2 = P.bemb[t];
                #pragma unroll
                for (int j = 0; j < AD; j++)
                    v2 += actv[j]*P.Wemb[j*DM + t];
                xL[t] = v2;
                yoL[t] = 0.f;
            }
            __syncthreads();
        }
    } // i
}

// ---------------- launch ----------------

extern "C" void kernel_launch(void* const* d_in, const int* in_sizes, int n_in,
                              void* d_out, int out_size, void* d_ws, size_t ws_size,
                              hipStream_t stream)
{
    const float* in[29];
    for (int k = 0; k < 29; k++) in[k] = (const float*)d_in[k];

    // workspace layout (bytes), total ~103 MB (ws is 256 MB per poison-fill evidence)
    char* wsb = (char*)d_ws;
    bf16*   W1b  = (bf16*)  (wsb + 0);           // 16,777,216
    uint32* WoU  = (uint32*)(wsb + 16777216);    //  8,388,608
    bf16*   Wxb  = (bf16*)  (wsb + 25165824);    //  1,572,864
    bf16*   Wdtb = (bf16*)  (wsb + 26738688);    //    524,288
    float*  negA = (float*) (wsb + 27262976);    //  1,048,576
    float*  ctx  = (float*) (wsb + 28311552);    //  2,097,152
    uint32* convrU = (uint32*)(wsb + 30408704);  //  8,388,608
    uint32* hG   = (uint32*)(wsb + 38797312);    // 67,108,864  (end 105,906,176)

    float* out = (float*)d_out;

    k_negA<<<dim3(1024),  256, 0, stream>>>(in[17], in[26], negA);
    k_ctx <<<dim3(B*NA),  256, 0, stream>>>(in[0], in[1], in[5], ctx);
    k_w1  <<<dim3(32768), 256, 0, stream>>>(in[11], in[20], (ushort16*)W1b);
    k_wo  <<<dim3(8192),  256, 0, stream>>>(in[19], in[28], WoU);
    k_wx  <<<dim3(3072),  256, 0, stream>>>(in[14], in[23], (ushort16*)Wxb);
    k_wdt <<<dim3(1024),  256, 0, stream>>>(in[15], in[24], (ushort16*)Wdtb);

    KP P;
    P.W1b = W1b;  P.Wxb = Wxb;  P.Wdtb = Wdtb;  P.WoU = WoU;
    P.negA = negA; P.ctxG = ctx;
    P.cw_s = in[12]; P.cb_s = in[13]; P.dtb_s = in[16]; P.D_s = in[18];
    P.cw_c = in[21]; P.cb_c = in[22]; P.dtb_c = in[25]; P.D_c = in[27];
    P.ln1 = in[6]; P.ln2 = in[7]; P.lno = in[8]; P.Whead = in[9];
    P.logstd = in[10]; P.eps = in[2]; P.Wemb = in[3]; P.bemb = in[4];
    P.out = out;
    P.convrU = convrU; P.hG = hG;

    k_row<<<dim3(B), dim3(1024), 0, stream>>>(P);
}

// Round 4
// 2460.650 us; speedup vs baseline: 2.6533x; 2.6533x over previous
//
#include <hip/hip_runtime.h>
#include <hip/hip_bf16.h>

#define B   128
#define NA  8
#define AD  16
#define DM  512
#define DI  1024
#define DS  32
#define DC  4
#define DR  32
#define NB  4
#define OD  128

typedef __hip_bfloat16 bf16;
typedef unsigned int uint32;
typedef unsigned short ushort16;

__device__ __forceinline__ float bf2f(bf16 h){ return __bfloat162float(h); }
__device__ __forceinline__ float sigmoidf_(float x){ return 1.0f/(1.0f+__expf(-x)); }
__device__ __forceinline__ float softplusf_(float x){ return fmaxf(x,0.0f)+log1pf(__expf(-fabsf(x))); }
__device__ __forceinline__ float lo2f(uint32 u){ return __uint_as_float(u<<16); }
__device__ __forceinline__ float hi2f(uint32 u){ return __uint_as_float(u & 0xffff0000u); }
__device__ __forceinline__ uint32 packbf2(float a, float b){
    bf16 ha = __float2bfloat16(a), hb = __float2bfloat16(b);
    ushort16 sa = *reinterpret_cast<ushort16*>(&ha);
    ushort16 sb = *reinterpret_cast<ushort16*>(&hb);
    return (uint32)sa | ((uint32)sb << 16);
}
__device__ __forceinline__ ushort16 f2us(float a){
    bf16 ha = __float2bfloat16(a);
    return *reinterpret_cast<ushort16*>(&ha);
}

// ---------------- init / conversion kernels (unchanged layouts) ----------------

__global__ __launch_bounds__(256) void k_negA(const float* __restrict__ Als,
    const float* __restrict__ Alc, float* __restrict__ negA)
{
    int idx = blockIdx.x*256 + threadIdx.x;   // < 2*NB*DI*DS = 262144
    int bs = idx >> 15;
    int r  = idx & 32767;
    int nb = bs >> 1, st = bs & 1;
    const float* src = (st ? Alc : Als) + (size_t)nb*DI*DS + r;
    negA[idx] = -__expf(*src);
}

__global__ __launch_bounds__(256) void k_ctx(const float* __restrict__ obs_rep,
    const float* __restrict__ obs, const float* __restrict__ Wobs,
    float* __restrict__ ctx)
{
    int ib = blockIdx.x;          // < B*8
    int b = ib >> 3, i = ib & 7;
    __shared__ float orow[OD];
    int tid = threadIdx.x;
    if (tid < OD) orow[tid] = obs[(size_t)(b*NA+i)*OD + tid];
    __syncthreads();
    for (int m = tid; m < DM; m += 256){
        float acc = obs_rep[(size_t)(b*NA+i)*DM + m];
        for (int o = 0; o < OD; o++)
            acc += orow[o]*Wobs[o*DM + m];
        ctx[(size_t)(i*B + b)*DM + m] = acc;
    }
}

// W1b[bs][k][c] bf16, [8][512][2048]
__global__ __launch_bounds__(256) void k_w1(const float* __restrict__ Ws,
    const float* __restrict__ Wc, ushort16* __restrict__ W1b)
{
    int idx = blockIdx.x*256 + threadIdx.x;   // < 8*1048576
    int bs = idx >> 20;
    int r  = idx & 1048575;
    int nb = bs >> 1, st = bs & 1;
    const float* src = (st ? Wc : Ws) + (size_t)nb*1048576 + r;
    W1b[idx] = f2us(*src);
}

// WoU[bs][k][p] = packed pair (cols 2p,2p+1) of out_proj (1024 x 512)
__global__ __launch_bounds__(256) void k_wo(const float* __restrict__ Ws,
    const float* __restrict__ Wc, uint32* __restrict__ WoU)
{
    int idx = blockIdx.x*256 + threadIdx.x;   // < 8*262144
    int bs = idx >> 18;
    int r  = idx & 262143;
    int k  = r >> 8, p = r & 255;
    int nb = bs >> 1, st = bs & 1;
    const float* src = (st ? Wc : Ws) + (size_t)nb*DI*DM + (size_t)k*DM + 2*p;
    WoU[idx] = packbf2(src[0], src[1]);
}

// Wxb[bs][j][k] bf16 — TRANSPOSED x_proj: [8][96][1024]
__global__ __launch_bounds__(256) void k_wx(const float* __restrict__ Ws,
    const float* __restrict__ Wc, ushort16* __restrict__ Wxb)
{
    int idx = blockIdx.x*256 + threadIdx.x;   // < 8*98304
    int bs = idx / 98304;
    int r  = idx % 98304;
    int j  = r >> 10, k = r & 1023;
    int nb = bs >> 1, st = bs & 1;
    const float* src = (st ? Wc : Ws) + (size_t)nb*DI*96 + (size_t)k*96 + j;
    Wxb[idx] = f2us(*src);
}

// Wdtb[bs][r][d] bf16 [8][32][1024]
__global__ __launch_bounds__(256) void k_wdt(const float* __restrict__ Ws,
    const float* __restrict__ Wc, ushort16* __restrict__ Wdtb)
{
    int idx = blockIdx.x*256 + threadIdx.x;   // < 8*32768
    int bs = idx >> 15;
    int r  = idx & 32767;
    int nb = bs >> 1, st = bs & 1;
    const float* src = (st ? Wc : Ws) + (size_t)nb*DR*DI + r;
    Wdtb[idx] = f2us(*src);
}

// x0 = bemb broadcast; zero 8 partial buffers pP[8][B][DM]
__global__ __launch_bounds__(256) void k_init(const float* __restrict__ bemb,
    float* __restrict__ xb0, float* __restrict__ pP)
{
    int idx = blockIdx.x*256 + threadIdx.x;   // < 8*B*DM = 524288
    if (idx < B*DM) xb0[idx] = bemb[idx & (DM-1)];
    pP[idx] = 0.f;
}

// ---------------- per-step kernels ----------------
// grid 256 = 32 rowgroups (R=4 rows) x 8 colgroups/chunks, 1024 threads
// (16 waves/CU = 4 waves/SIMD for latency hiding on the weight stream).

// step1: fold x + sum(pP), LN(+ctx), gemm1 (256-col slice, 8x64 K-chunks,
// unroll 8 -> 8 uint4 loads in flight), conv ring + silu -> xc (cg<4),
// xproj partial slice (cg<4), sz (cg>=4)
__global__ __launch_bounds__(1024) void k_step1(
    const float* __restrict__ xin, const float* __restrict__ pP,
    float* __restrict__ xout, const float* __restrict__ lns,
    const float* __restrict__ ctxG, const bf16* __restrict__ W1b,
    const bf16* __restrict__ Wxb, const float* __restrict__ cw,
    const float* __restrict__ cb, uint32* __restrict__ convrU,
    float* __restrict__ xcG, float* __restrict__ szG,
    float* __restrict__ xpP, int i, int st, int bs)
{
    int rg = blockIdx.x >> 3, cg = blockIdx.x & 7;
    int t = threadIdx.x;
    __shared__ float ulnL[4][512];
    __shared__ float red1[8][4][256];   // [kchunk][row][col]
    __shared__ float xzL[4][256];       // later reused to hold xc (cg<4)
    __shared__ float wred[4][2][2];
    __shared__ float ms2[4][2];

    // ---- fold + LN (t<512: row r of 4, 4 consecutive cols) ----
    {
        int r = (t >> 7) & 3, cq = t & 127;
        int row = rg*4 + r;
        float4 v4 = make_float4(0.f,0.f,0.f,0.f);
        if (t < 512){
            v4 = *(const float4*)&xin[(size_t)row*DM + cq*4];
            #pragma unroll
            for (int g = 0; g < 8; g++){
                float4 q4 = *(const float4*)&pP[((size_t)g*B + row)*DM + cq*4];
                v4.x += q4.x; v4.y += q4.y; v4.z += q4.z; v4.w += q4.w;
            }
            if (cg == 0) *(float4*)&xout[(size_t)row*DM + cq*4] = v4;
            float sv = v4.x + v4.y + v4.z + v4.w;
            float qv = v4.x*v4.x + v4.y*v4.y + v4.z*v4.z + v4.w*v4.w;
            #pragma unroll
            for (int off = 32; off > 0; off >>= 1){
                sv += __shfl_down(sv, off);
                qv += __shfl_down(qv, off);
            }
            int lane = t & 63, wid = t >> 6;   // wid 0..7
            if (lane == 0){ wred[wid>>1][wid&1][0] = sv; wred[wid>>1][wid&1][1] = qv; }
        }
        __syncthreads();
        if (t < 4){
            float S = wred[t][0][0] + wred[t][1][0];
            float Q = wred[t][0][1] + wred[t][1][1];
            float m = S*(1.0f/DM);
            float var = Q*(1.0f/DM) - m*m;
            ms2[t][0] = m; ms2[t][1] = rsqrtf(var + 1e-5f);
        }
        __syncthreads();
        if (t < 512){
            float m = ms2[r][0], rs = ms2[r][1];
            float4 l4 = *(const float4*)&lns[cq*4];
            float u0 = (v4.x - m)*rs*l4.x;
            float u1 = (v4.y - m)*rs*l4.y;
            float u2 = (v4.z - m)*rs*l4.z;
            float u3 = (v4.w - m)*rs*l4.w;
            if (st){
                float4 c4 = *(const float4*)&ctxG[((size_t)i*B + row)*DM + cq*4];
                u0 += c4.x; u1 += c4.y; u2 += c4.z; u3 += c4.w;
            }
            *(float4*)&ulnL[r][cq*4] = make_float4(u0,u1,u2,u3);
        }
    }
    __syncthreads();

    // ---- gemm1: thread = (pack p of 32, row rr of 4, kchunk g of 8x64) ----
    {
        int p = t & 31, rr = (t>>5)&3, g = t >> 7;   // g 0..7
        const uint4* wp4 = (const uint4*)(W1b + ((size_t)bs << 20));
        const float* ur = ulnL[rr];
        float a0=0.f,a1=0.f,a2=0.f,a3=0.f,a4=0.f,a5=0.f,a6=0.f,a7=0.f;
        int kbeg = g*64;
        size_t widx = (size_t)kbeg*256 + cg*32 + p;
        #pragma unroll 8
        for (int k = kbeg; k < kbeg + 64; k++, widx += 256){
            float a = ur[k];
            uint4 q4 = wp4[widx];
            a0 += a*lo2f(q4.x); a1 += a*hi2f(q4.x);
            a2 += a*lo2f(q4.y); a3 += a*hi2f(q4.y);
            a4 += a*lo2f(q4.z); a5 += a*hi2f(q4.z);
            a6 += a*lo2f(q4.w); a7 += a*hi2f(q4.w);
        }
        *(float4*)&red1[g][rr][p*8]     = make_float4(a0,a1,a2,a3);
        *(float4*)&red1[g][rr][p*8 + 4] = make_float4(a4,a5,a6,a7);
    }
    __syncthreads();
    {
        int r2 = t >> 8, c = t & 255;
        xzL[r2][c] = ((red1[0][r2][c] + red1[1][r2][c])
                   +  (red1[2][r2][c] + red1[3][r2][c]))
                   + ((red1[4][r2][c] + red1[5][r2][c])
                   +  (red1[6][r2][c] + red1[7][r2][c]));
    }
    __syncthreads();

    if (cg < 4){
        // ---- conv ring + silu -> xc (t<512) ----
        if (t < 512){
            int r3 = (t >> 7) & 3, pi = t & 127;
            int row3 = rg*4 + r3;
            int d0 = cg*256 + 2*pi;
            float xz0 = xzL[r3][2*pi], xz1 = xzL[r3][2*pi+1];
            uint32* ring = convrU + ((size_t)bs << 18);   // [4][128][512] uints
            size_t rb = (size_t)row3*512 + (d0>>1);
            ring[((size_t)(i&3))*65536 + rb] = packbf2(xz0, xz1);
            float s0 = cb[d0]   + cw[3*DI + d0]  *xz0;
            float s1 = cb[d0+1] + cw[3*DI + d0+1]*xz1;
            if (i >= 1){ uint32 uu = ring[((size_t)((i-1)&3))*65536 + rb];
                s0 += cw[2*DI + d0]*lo2f(uu); s1 += cw[2*DI + d0+1]*hi2f(uu); }
            if (i >= 2){ uint32 uu = ring[((size_t)((i-2)&3))*65536 + rb];
                s0 += cw[1*DI + d0]*lo2f(uu); s1 += cw[1*DI + d0+1]*hi2f(uu); }
            if (i >= 3){ uint32 uu = ring[((size_t)((i-3)&3))*65536 + rb];
                s0 += cw[0*DI + d0]*lo2f(uu); s1 += cw[0*DI + d0+1]*hi2f(uu); }
            float xc0 = s0*sigmoidf_(s0), xc1 = s1*sigmoidf_(s1);
            xcG[(size_t)row3*DI + d0]   = xc0;
            xcG[(size_t)row3*DI + d0+1] = xc1;
            xzL[r3][2*pi] = xc0; xzL[r3][2*pi+1] = xc1;  // own slots: no race
        }
        __syncthreads();
        // ---- xproj partial over this 256-k slice ----
        if (t < 384){
            int rx = t/96, j = t - rx*96;
            const uint4* wx4 = (const uint4*)(Wxb + (size_t)bs*98304
                                              + (size_t)j*1024 + cg*256);
            const float* xr = xzL[rx];
            float acc = 0.f;
            #pragma unroll 8
            for (int ii = 0; ii < 32; ii++){
                uint4 q4 = wx4[ii];
                int kk = 8*ii;
                acc += xr[kk+0]*lo2f(q4.x) + xr[kk+1]*hi2f(q4.x)
                     + xr[kk+2]*lo2f(q4.y) + xr[kk+3]*hi2f(q4.y)
                     + xr[kk+4]*lo2f(q4.z) + xr[kk+5]*hi2f(q4.z)
                     + xr[kk+6]*lo2f(q4.w) + xr[kk+7]*hi2f(q4.w);
            }
            xpP[((size_t)cg*B + rg*4 + rx)*96 + j] = acc;
        }
    } else {
        // ---- z path: sz ----
        int r2 = t >> 8, c = t & 255;
        int row2 = rg*4 + r2;
        int d = (cg-4)*256 + c;
        float xz = xzL[r2][c];
        szG[(size_t)row2*DI + d] = xz*sigmoidf_(xz);
    }
}

// step2: rowS from 4 xproj slices, dt, h update + y (128-d chunk x 4 rows),
// gemm2 K-chunk (4x32 split, uint4 weight reads) -> pP[g]
// h layout: [bs][row][qq(4)][d(1024)] uint4 — lane-coalesced.
__global__ __launch_bounds__(1024) void k_step2(
    const float* __restrict__ xcG, const float* __restrict__ szG,
    const float* __restrict__ xpP, const bf16* __restrict__ Wdtb,
    const float* __restrict__ dtb, const float* __restrict__ Dp,
    const float* __restrict__ negA, const uint32* __restrict__ WoU,
    uint32* __restrict__ hG, float* __restrict__ pP,
    int first, int bs)
{
    int rg = blockIdx.x >> 3, g = blockIdx.x & 7;
    int t = threadIdx.x;
    __shared__ float rowS[4][96];
    __shared__ float yzL[4][128];
    __shared__ float red2[4][4][512];   // [ksplit][row][col]

    if (t < 384){
        int rx = t/96, j = t - rx*96;
        int row0 = rg*4 + rx;
        size_t base = (size_t)row0*96 + j;
        rowS[rx][j] = xpP[base] + xpP[(size_t)B*96 + base]
                    + xpP[(size_t)2*B*96 + base] + xpP[(size_t)3*B*96 + base];
    }
    __syncthreads();

    if (t < 512){
        int r = (t >> 7) & 3, dl = t & 127;
        int d = g*128 + dl;
        int row = rg*4 + r;
        float dp = dtb[d];
        const bf16* wdt = Wdtb + ((size_t)bs << 15);
        #pragma unroll 8
        for (int rr = 0; rr < DR; rr++)
            dp += rowS[r][rr]*bf2f(wdt[(size_t)rr*DI + d]);
        float delta = softplusf_(dp);
        float xcv = xcG[(size_t)row*DI + d];
        float dxc = delta*xcv;
        const float4* nap = (const float4*)(negA + ((size_t)bs << 15) + (size_t)d*DS);
        uint4* hb = ((uint4*)hG) + ((size_t)(bs*B + row) << 12) + d;  // [qq][1024]
        float y = 0.f;
        #pragma unroll
        for (int qq = 0; qq < 4; qq++){
            uint4 hu = first ? make_uint4(0u,0u,0u,0u) : hb[qq << 10];
            float4 na0 = nap[2*qq], na1 = nap[2*qq+1];
            int s0 = 8*qq;
            float h0 = lo2f(hu.x), h1 = hi2f(hu.x);
            float h2 = lo2f(hu.y), h3 = hi2f(hu.y);
            float h4 = lo2f(hu.z), h5 = hi2f(hu.z);
            float h6 = lo2f(hu.w), h7 = hi2f(hu.w);
            h0 = __expf(delta*na0.x)*h0 + dxc*rowS[r][DR+s0+0];
            h1 = __expf(delta*na0.y)*h1 + dxc*rowS[r][DR+s0+1];
            h2 = __expf(delta*na0.z)*h2 + dxc*rowS[r][DR+s0+2];
            h3 = __expf(delta*na0.w)*h3 + dxc*rowS[r][DR+s0+3];
            h4 = __expf(delta*na1.x)*h4 + dxc*rowS[r][DR+s0+4];
            h5 = __expf(delta*na1.y)*h5 + dxc*rowS[r][DR+s0+5];
            h6 = __expf(delta*na1.z)*h6 + dxc*rowS[r][DR+s0+6];
            h7 = __expf(delta*na1.w)*h7 + dxc*rowS[r][DR+s0+7];
            y += h0*rowS[r][DR+DS+s0+0] + h1*rowS[r][DR+DS+s0+1]
               + h2*rowS[r][DR+DS+s0+2] + h3*rowS[r][DR+DS+s0+3]
               + h4*rowS[r][DR+DS+s0+4] + h5*rowS[r][DR+DS+s0+5]
               + h6*rowS[r][DR+DS+s0+6] + h7*rowS[r][DR+DS+s0+7];
            hu.x = packbf2(h0,h1); hu.y = packbf2(h2,h3);
            hu.z = packbf2(h4,h5); hu.w = packbf2(h6,h7);
            hb[qq << 10] = hu;
        }
        y += Dp[d]*xcv;
        yzL[r][dl] = y*szG[(size_t)row*DI + d];
    }
    __syncthreads();

    // gemm2: thread = (colquad c of 64 -> 8 cols, row r2 of 4, ksplit ks of 4x32)
    {
        int c = t & 63, r2 = (t>>6)&3, ks = t >> 8;
        const uint4* wo4 = (const uint4*)(WoU + ((size_t)bs << 18));
        const float* yr = yzL[r2];
        float b0=0.f,b1=0.f,b2=0.f,b3=0.f,b4=0.f,b5=0.f,b6=0.f,b7=0.f;
        int kb = g*128 + ks*32, kl0 = ks*32;
        #pragma unroll 8
        for (int kk = 0; kk < 32; kk++){
            float av = yr[kl0 + kk];
            uint4 u4 = wo4[(size_t)(kb + kk)*64 + c];
            b0 += av*lo2f(u4.x); b1 += av*hi2f(u4.x);
            b2 += av*lo2f(u4.y); b3 += av*hi2f(u4.y);
            b4 += av*lo2f(u4.z); b5 += av*hi2f(u4.z);
            b6 += av*lo2f(u4.w); b7 += av*hi2f(u4.w);
        }
        *(float4*)&red2[ks][r2][c*8]     = make_float4(b0,b1,b2,b3);
        *(float4*)&red2[ks][r2][c*8 + 4] = make_float4(b4,b5,b6,b7);
    }
    __syncthreads();
    if (t < 512){
        int r2 = t >> 7, c = t & 127;
        int row2 = rg*4 + r2;
        float4 s0 = *(float4*)&red2[0][r2][4*c];
        float4 s1 = *(float4*)&red2[1][r2][4*c];
        float4 s2 = *(float4*)&red2[2][r2][4*c];
        float4 s3 = *(float4*)&red2[3][r2][4*c];
        float4 pv = make_float4(s0.x+s1.x+s2.x+s3.x, s0.y+s1.y+s2.y+s3.y,
                                s0.z+s1.z+s2.z+s3.z, s0.w+s1.w+s2.w+s3.w);
        *(float4*)&pP[((size_t)g*B + row2)*DM + 4*c] = pv;
    }
}

// head: fold(8 partials), LN, W_head GEMV, outputs, next x, zero partials
__global__ __launch_bounds__(512) void k_head(
    const float* __restrict__ xin, float* __restrict__ xout,
    float* __restrict__ pP,
    const float* __restrict__ lno, const float* __restrict__ Whead,
    const float* __restrict__ logstd, const float* __restrict__ eps,
    const float* __restrict__ Wemb, const float* __restrict__ bemb,
    float* __restrict__ out, int agent)
{
    int b = blockIdx.x, t = threadIdx.x, lane = t & 63, wid = t >> 6;
    __shared__ float ulnL[512];
    __shared__ float redH[512];
    __shared__ float wps[8], wpq[8], ms2[2];
    __shared__ float actv[AD], lpterm[AD];

    float v = xin[(size_t)b*DM + t];
    #pragma unroll
    for (int g = 0; g < 8; g++) v += pP[((size_t)g*B + b)*DM + t];
    float s = v, q = v*v;
    for (int off = 32; off > 0; off >>= 1){
        s += __shfl_down(s, off);
        q += __shfl_down(q, off);
    }
    if (lane == 0){ wps[wid] = s; wpq[wid] = q; }
    __syncthreads();
    if (t == 0){
        float S = 0.f, Q = 0.f;
        #pragma unroll
        for (int w2 = 0; w2 < 8; w2++){ S += wps[w2]; Q += wpq[w2]; }
        float m = S*(1.0f/DM);
        float var = Q*(1.0f/DM) - m*m;
        ms2[0] = m; ms2[1] = rsqrtf(var + 1e-5f);
    }
    __syncthreads();
    ulnL[t] = (v - ms2[0])*ms2[1]*lno[t];
    __syncthreads();
    {
        int ks = t >> 4, j = t & 15;
        float acc = 0.f;
        int k0 = ks*16;
        #pragma unroll
        for (int k = k0; k < k0 + 16; k++)
            acc += ulnL[k]*Whead[k*AD + j];
        redH[t] = acc;
    }
    __syncthreads();
    if (t < AD){
        int j = t;
        float mean = 0.f;
        #pragma unroll
        for (int ks = 0; ks < 32; ks++) mean += redH[ks*16 + j];
        float stdj = softplusf_(logstd[j]);
        float e = eps[((size_t)b*NA + agent)*AD + j];
        float raw = mean + stdj*e;
        float act = tanhf(raw);
        out[((size_t)b*NA + agent)*AD + j] = act;                                    // acts
        out[(size_t)NA*B*AD + (size_t)B*NA + ((size_t)b*NA + agent)*AD + j] = raw;   // raws
        actv[j] = act;
        lpterm[j] = -0.5f*e*e - logf(stdj)
                    - 2.0f*(0.69314718f - raw - softplusf_(-2.0f*raw));
    }
    __syncthreads();
    if (t == 0){
        float lp = 0.f;
        #pragma unroll
        for (int j = 0; j < AD; j++) lp += lpterm[j];
        lp -= 0.5f*AD*1.8378770664f;
        out[(size_t)NA*B*AD + (size_t)b*NA + agent] = lp;                            // logs
    }
    float v2 = bemb[t];
    #pragma unroll
    for (int j = 0; j < AD; j++)
        v2 += actv[j]*Wemb[j*DM + t];
    xout[(size_t)b*DM + t] = v2;
    #pragma unroll
    for (int g = 0; g < 8; g++) pP[((size_t)g*B + b)*DM + t] = 0.f;
}

// ---------------- launch ----------------

extern "C" void kernel_launch(void* const* d_in, const int* in_sizes, int n_in,
                              void* d_out, int out_size, void* d_ws, size_t ws_size,
                              hipStream_t stream)
{
    const float* in[29];
    for (int k = 0; k < 29; k++) in[k] = (const float*)d_in[k];

    // workspace layout (bytes), total ~110 MB (ws is 256 MB per poison-fill evidence)
    char* wsb = (char*)d_ws;
    bf16*   W1b  = (bf16*)  (wsb + 0);           // 16,777,216
    uint32* WoU  = (uint32*)(wsb + 16777216);    //  8,388,608
    bf16*   Wxb  = (bf16*)  (wsb + 25165824);    //  1,572,864
    bf16*   Wdtb = (bf16*)  (wsb + 26738688);    //    524,288
    float*  negA = (float*) (wsb + 27262976);    //  1,048,576
    float*  ctx  = (float*) (wsb + 28311552);    //  2,097,152
    float*  xb0  = (float*) (wsb + 30408704);    //    262,144
    float*  xb1  = (float*) (wsb + 30670848);    //    262,144
    float*  xcG  = (float*) (wsb + 30932992);    //    524,288
    float*  szG  = (float*) (wsb + 31457280);    //    524,288
    float*  xpP  = (float*) (wsb + 31981568);    //    262,144 (uses 196,608)
    float*  pP   = (float*) (wsb + 32243712);    //  2,097,152  [8][B][DM]
    uint32* convrU = (uint32*)(wsb + 34340864);  //  8,388,608
    uint32* hG   = (uint32*)(wsb + 42729472);    // 67,108,864  [bs][row][qq][d] uint4

    float* out = (float*)d_out;
    float* xb[2] = {xb0, xb1};

    k_negA<<<dim3(1024),  256, 0, stream>>>(in[17], in[26], negA);
    k_ctx <<<dim3(B*NA),  256, 0, stream>>>(in[0], in[1], in[5], ctx);
    k_w1  <<<dim3(32768), 256, 0, stream>>>(in[11], in[20], (ushort16*)W1b);
    k_wo  <<<dim3(8192),  256, 0, stream>>>(in[19], in[28], WoU);
    k_wx  <<<dim3(3072),  256, 0, stream>>>(in[14], in[23], (ushort16*)Wxb);
    k_wdt <<<dim3(1024),  256, 0, stream>>>(in[15], in[24], (ushort16*)Wdtb);
    k_init<<<dim3(2048),  256, 0, stream>>>(in[4], xb0, pP);

    int cur = 0;
    for (int i = 0; i < NA; i++){
        for (int nb = 0; nb < NB; nb++){
            for (int st = 0; st < 2; st++){
                int bs = nb*2 + st;
                int base = st ? 20 : 11;
                const float* cw   = in[base+1] + (size_t)nb*DC*DI;
                const float* cb   = in[base+2] + (size_t)nb*DI;
                const float* dtbp = in[base+5] + (size_t)nb*DI;
                const float* Dpp  = in[base+7] + (size_t)nb*DI;
                const float* lns  = (st ? in[7] : in[6]) + (size_t)nb*DM;

                k_step1<<<dim3(256), 1024, 0, stream>>>(xb[cur], pP, xb[cur^1],
                        lns, ctx, W1b, Wxb, cw, cb, convrU, xcG, szG, xpP, i, st, bs);
                cur ^= 1;
                k_step2<<<dim3(256), 1024, 0, stream>>>(xcG, szG, xpP, Wdtb,
                        dtbp, Dpp, negA, WoU, hG, pP, (i==0) ? 1 : 0, bs);
            }
        }
        k_head<<<dim3(B), 512, 0, stream>>>(xb[cur], xb[cur^1], pP,
                in[8], in[9], in[10], in[2], in[3], in[4], out, i);
        cur ^= 1;
    }
}

// Round 5
// 2329.187 us; speedup vs baseline: 2.8030x; 1.0564x over previous
//
#include <hip/hip_runtime.h>
#include <hip/hip_bf16.h>

#define B   128
#define NA  8
#define AD  16
#define DM  512
#define DI  1024
#define DS  32
#define DC  4
#define DR  32
#define NB  4
#define OD  128

typedef unsigned int uint32;
typedef _Float16 h2f __attribute__((ext_vector_type(2)));

__device__ __forceinline__ float sigmoidf_(float x){ return 1.0f/(1.0f+__expf(-x)); }
__device__ __forceinline__ float softplusf_(float x){ return fmaxf(x,0.0f)+log1pf(__expf(-fabsf(x))); }

// f16 pair helpers: one uint32 = half2 (lo = first, hi = second)
__device__ __forceinline__ float dot2h(uint32 a, uint32 b, float c){
    union { uint32 u; h2f h; } ua, ub;
    ua.u = a; ub.u = b;
#if __has_builtin(__builtin_amdgcn_fdot2)
    return __builtin_amdgcn_fdot2(ua.h, ub.h, c, false);
#else
    return c + (float)ua.h.x*(float)ub.h.x + (float)ua.h.y*(float)ub.h.y;
#endif
}
__device__ __forceinline__ uint32 packh2(float a, float b){
    union { uint32 u; h2f h; } w;
    w.h.x = (_Float16)a; w.h.y = (_Float16)b;
    return w.u;
}
__device__ __forceinline__ float loh(uint32 u){
    union { uint32 uu; h2f h; } w; w.uu = u; return (float)w.h.x;
}
__device__ __forceinline__ float hih(uint32 u){
    union { uint32 uu; h2f h; } w; w.uu = u; return (float)w.h.y;
}

// ---------------- init / conversion kernels ----------------

__global__ __launch_bounds__(256) void k_negA(const float* __restrict__ Als,
    const float* __restrict__ Alc, float* __restrict__ negA)
{
    int idx = blockIdx.x*256 + threadIdx.x;   // < 2*NB*DI*DS = 262144
    int bs = idx >> 15;
    int r  = idx & 32767;
    int nb = bs >> 1, st = bs & 1;
    const float* src = (st ? Alc : Als) + (size_t)nb*DI*DS + r;
    negA[idx] = -__expf(*src);
}

__global__ __launch_bounds__(256) void k_ctx(const float* __restrict__ obs_rep,
    const float* __restrict__ obs, const float* __restrict__ Wobs,
    float* __restrict__ ctx)
{
    int ib = blockIdx.x;          // < B*8
    int b = ib >> 3, i = ib & 7;
    __shared__ float orow[OD];
    int tid = threadIdx.x;
    if (tid < OD) orow[tid] = obs[(size_t)(b*NA+i)*OD + tid];
    __syncthreads();
    for (int m = tid; m < DM; m += 256){
        float acc = obs_rep[(size_t)(b*NA+i)*DM + m];
        for (int o = 0; o < OD; o++)
            acc += orow[o]*Wobs[o*DM + m];
        ctx[(size_t)(i*B + b)*DM + m] = acc;
    }
}

// W1H[bs][k2][c] uint32 = half2(W[2k2][c], W[2k2+1][c]); [8][256][2048]
__global__ __launch_bounds__(256) void k_w1h(const float* __restrict__ Ws,
    const float* __restrict__ Wc, uint32* __restrict__ W1H)
{
    int idx = blockIdx.x*256 + threadIdx.x;   // < 8*524288
    int bs = idx >> 19;
    int r  = idx & 524287;
    int k2 = r >> 11, c = r & 2047;
    int nb = bs >> 1, st = bs & 1;
    const float* src = (st ? Wc : Ws) + (size_t)nb*1048576 + (size_t)(2*k2)*2048 + c;
    W1H[idx] = packh2(src[0], src[2048]);
}

// WoH[bs][k2][c] uint32 = half2(Wo[2k2][c], Wo[2k2+1][c]); [8][512][512]
__global__ __launch_bounds__(256) void k_woh(const float* __restrict__ Ws,
    const float* __restrict__ Wc, uint32* __restrict__ WoH)
{
    int idx = blockIdx.x*256 + threadIdx.x;   // < 8*262144
    int bs = idx >> 18;
    int r  = idx & 262143;
    int k2 = r >> 9, c = r & 511;
    int nb = bs >> 1, st = bs & 1;
    const float* src = (st ? Wc : Ws) + (size_t)nb*DI*DM + (size_t)(2*k2)*DM + c;
    WoH[idx] = packh2(src[0], src[DM]);
}

// WxH[bs][j][k2] uint32 = half2(X[2k2][j], X[2k2+1][j]); [8][96][512]
__global__ __launch_bounds__(256) void k_wxh(const float* __restrict__ Ws,
    const float* __restrict__ Wc, uint32* __restrict__ WxH)
{
    int idx = blockIdx.x*256 + threadIdx.x;   // < 8*49152
    int bs = idx / 49152;
    int r  = idx % 49152;
    int j  = r >> 9, k2 = r & 511;
    int nb = bs >> 1, st = bs & 1;
    const float* src = (st ? Wc : Ws) + (size_t)nb*DI*96 + (size_t)(2*k2)*96 + j;
    WxH[idx] = packh2(src[0], src[96]);
}

// WdtH[bs][r2][d] uint32 = half2(Wd[2r2][d], Wd[2r2+1][d]); [8][16][1024]
__global__ __launch_bounds__(256) void k_wdth(const float* __restrict__ Ws,
    const float* __restrict__ Wc, uint32* __restrict__ WdtH)
{
    int idx = blockIdx.x*256 + threadIdx.x;   // < 8*16384
    int bs = idx >> 14;
    int r  = idx & 16383;
    int r2 = r >> 10, d = r & 1023;
    int nb = bs >> 1, st = bs & 1;
    const float* src = (st ? Wc : Ws) + (size_t)nb*DR*DI + (size_t)(2*r2)*DI + d;
    WdtH[idx] = packh2(src[0], src[DI]);
}

// x0 = bemb broadcast; zero 8 partial buffers pP[8][B][DM]
__global__ __launch_bounds__(256) void k_init(const float* __restrict__ bemb,
    float* __restrict__ xb0, float* __restrict__ pP)
{
    int idx = blockIdx.x*256 + threadIdx.x;   // < 8*B*DM = 524288
    if (idx < B*DM) xb0[idx] = bemb[idx & (DM-1)];
    pP[idx] = 0.f;
}

// ---------------- per-step kernels ----------------
// grid 256 = 32 rowgroups (R=4 rows) x 8 colgroups/chunks, 1024 threads.
// All GEMV inner loops use v_dot2_f32_f16 on packed f16 k-pairs.

// step1: fold x + sum(pP), LN(+ctx) -> packed f16 pairs, gemm1 (256-col slice,
// 4x128 K-chunks via dot2), conv ring + silu -> xc (cg<4), xproj slice (cg<4),
// sz (cg>=4)
__global__ __launch_bounds__(1024) void k_step1(
    const float* __restrict__ xin, const float* __restrict__ pP,
    float* __restrict__ xout, const float* __restrict__ lns,
    const float* __restrict__ ctxG, const uint32* __restrict__ W1H,
    const uint32* __restrict__ WxH, const float* __restrict__ cw,
    const float* __restrict__ cb, uint32* __restrict__ convrU,
    float* __restrict__ xcG, float* __restrict__ szG,
    float* __restrict__ xpP, int i, int st, int bs)
{
    int rg = blockIdx.x >> 3, cg = blockIdx.x & 7;
    int t = threadIdx.x;
    __shared__ uint32 ulnP[4][256];     // f16 k-pairs of uln, per row
    __shared__ float red1[4][4][256];   // [kchunk][row][col]
    __shared__ float xzL[4][256];
    __shared__ uint32 xcP[4][128];      // f16 k-pairs of xc slice, per row
    __shared__ float wred[4][2][2];
    __shared__ float ms2[4][2];

    // ---- fold + LN (t<512: row r of 4, 4 consecutive cols) ----
    {
        int r = (t >> 7) & 3, cq = t & 127;
        int row = rg*4 + r;
        float4 v4 = make_float4(0.f,0.f,0.f,0.f);
        if (t < 512){
            v4 = *(const float4*)&xin[(size_t)row*DM + cq*4];
            #pragma unroll
            for (int g = 0; g < 8; g++){
                float4 q4 = *(const float4*)&pP[((size_t)g*B + row)*DM + cq*4];
                v4.x += q4.x; v4.y += q4.y; v4.z += q4.z; v4.w += q4.w;
            }
            if (cg == 0) *(float4*)&xout[(size_t)row*DM + cq*4] = v4;
            float sv = v4.x + v4.y + v4.z + v4.w;
            float qv = v4.x*v4.x + v4.y*v4.y + v4.z*v4.z + v4.w*v4.w;
            #pragma unroll
            for (int off = 32; off > 0; off >>= 1){
                sv += __shfl_down(sv, off);
                qv += __shfl_down(qv, off);
            }
            int lane = t & 63, wid = t >> 6;   // wid 0..7
            if (lane == 0){ wred[wid>>1][wid&1][0] = sv; wred[wid>>1][wid&1][1] = qv; }
        }
        __syncthreads();
        if (t < 4){
            float S = wred[t][0][0] + wred[t][1][0];
            float Q = wred[t][0][1] + wred[t][1][1];
            float m = S*(1.0f/DM);
            float var = Q*(1.0f/DM) - m*m;
            ms2[t][0] = m; ms2[t][1] = rsqrtf(var + 1e-5f);
        }
        __syncthreads();
        if (t < 512){
            float m = ms2[r][0], rs = ms2[r][1];
            float4 l4 = *(const float4*)&lns[cq*4];
            float u0 = (v4.x - m)*rs*l4.x;
            float u1 = (v4.y - m)*rs*l4.y;
            float u2 = (v4.z - m)*rs*l4.z;
            float u3 = (v4.w - m)*rs*l4.w;
            if (st){
                float4 c4 = *(const float4*)&ctxG[((size_t)i*B + row)*DM + cq*4];
                u0 += c4.x; u1 += c4.y; u2 += c4.z; u3 += c4.w;
            }
            ulnP[r][2*cq]   = packh2(u0, u1);
            ulnP[r][2*cq+1] = packh2(u2, u3);
        }
    }
    __syncthreads();

    // ---- gemm1: thread = (colquad p of 64, row rr of 4, k2-chunk g of 4x64) ----
    {
        int p = t & 63, rr = (t >> 6) & 3, g = t >> 8;   // g 0..3
        const uint32* w1 = W1H + ((size_t)bs << 19);     // [256 k2][2048 c]
        int k2b = g*64;
        const uint4* wp = (const uint4*)(w1 + ((size_t)k2b << 11)) + (cg*64 + p);
        const uint32* up = &ulnP[rr][k2b];
        float a0=0.f,a1=0.f,a2=0.f,a3=0.f;
        #pragma unroll 8
        for (int k2 = 0; k2 < 64; k2++){
            uint4 q = wp[(size_t)k2*512];
            uint32 ua = up[k2];
            a0 = dot2h(ua, q.x, a0);
            a1 = dot2h(ua, q.y, a1);
            a2 = dot2h(ua, q.z, a2);
            a3 = dot2h(ua, q.w, a3);
        }
        *(float4*)&red1[g][rr][4*p] = make_float4(a0,a1,a2,a3);
    }
    __syncthreads();
    {
        int r2 = t >> 8, c = t & 255;
        xzL[r2][c] = (red1[0][r2][c] + red1[1][r2][c])
                   + (red1[2][r2][c] + red1[3][r2][c]);
    }
    __syncthreads();

    if (cg < 4){
        // ---- conv ring + silu -> xc (t<512) ----
        if (t < 512){
            int r3 = (t >> 7) & 3, pi = t & 127;
            int row3 = rg*4 + r3;
            int d0 = cg*256 + 2*pi;
            float xz0 = xzL[r3][2*pi], xz1 = xzL[r3][2*pi+1];
            uint32* ring = convrU + ((size_t)bs << 18);   // [4][128][512] uints (f16 pairs)
            size_t rb = (size_t)row3*512 + (d0>>1);
            ring[((size_t)(i&3))*65536 + rb] = packh2(xz0, xz1);
            float s0 = cb[d0]   + cw[3*DI + d0]  *xz0;
            float s1 = cb[d0+1] + cw[3*DI + d0+1]*xz1;
            if (i >= 1){ uint32 uu = ring[((size_t)((i-1)&3))*65536 + rb];
                s0 += cw[2*DI + d0]*loh(uu); s1 += cw[2*DI + d0+1]*hih(uu); }
            if (i >= 2){ uint32 uu = ring[((size_t)((i-2)&3))*65536 + rb];
                s0 += cw[1*DI + d0]*loh(uu); s1 += cw[1*DI + d0+1]*hih(uu); }
            if (i >= 3){ uint32 uu = ring[((size_t)((i-3)&3))*65536 + rb];
                s0 += cw[0*DI + d0]*loh(uu); s1 += cw[0*DI + d0+1]*hih(uu); }
            float xc0 = s0*sigmoidf_(s0), xc1 = s1*sigmoidf_(s1);
            xcG[(size_t)row3*DI + d0]   = xc0;
            xcG[(size_t)row3*DI + d0+1] = xc1;
            xcP[r3][pi] = packh2(xc0, xc1);
        }
        __syncthreads();
        // ---- xproj partial over this 256-k slice (128 k2, dot2) ----
        if (t < 384){
            int rx = t/96, j = t - rx*96;
            const uint4* wx = (const uint4*)(WxH + (size_t)bs*49152
                                             + ((size_t)j << 9) + (cg << 7));
            const uint32* xr = xcP[rx];
            float acc = 0.f;
            #pragma unroll 8
            for (int ii = 0; ii < 32; ii++){
                uint4 q = wx[ii];
                acc = dot2h(xr[4*ii+0], q.x, acc);
                acc = dot2h(xr[4*ii+1], q.y, acc);
                acc = dot2h(xr[4*ii+2], q.z, acc);
                acc = dot2h(xr[4*ii+3], q.w, acc);
            }
            xpP[((size_t)cg*B + rg*4 + rx)*96 + j] = acc;
        }
    } else {
        // ---- z path: sz ----
        int r2 = t >> 8, c = t & 255;
        int row2 = rg*4 + r2;
        int d = (cg-4)*256 + c;
        float xz = xzL[r2][c];
        szG[(size_t)row2*DI + d] = xz*sigmoidf_(xz);
    }
}

// step2: rowS from 4 xproj slices, dt (dot2), h update + y (128-d chunk x 4 rows),
// gemm2 K-chunk (2x32 k2 split, dot2) -> pP[g]
// h layout: [bs][row][qq(4)][d(1024)] uint4 of f16 pairs — lane-coalesced.
__global__ __launch_bounds__(1024) void k_step2(
    const float* __restrict__ xcG, const float* __restrict__ szG,
    const float* __restrict__ xpP, const uint32* __restrict__ WdtH,
    const float* __restrict__ dtb, const float* __restrict__ Dp,
    const float* __restrict__ negA, const uint32* __restrict__ WoH,
    uint32* __restrict__ hG, float* __restrict__ pP,
    int first, int bs)
{
    int rg = blockIdx.x >> 3, g = blockIdx.x & 7;
    int t = threadIdx.x;
    __shared__ float rowS[4][96];
    __shared__ uint32 rowSP[4][16];     // f16 pairs of rowS[0..31] (dt input)
    __shared__ float yzL[4][128];
    __shared__ uint32 yzP[4][64];       // f16 pairs of yz chunk
    __shared__ float red2[2][4][512];   // [ksplit][row][col]

    if (t < 384){
        int rx = t/96, j = t - rx*96;
        int row0 = rg*4 + rx;
        size_t base = (size_t)row0*96 + j;
        rowS[rx][j] = xpP[base] + xpP[(size_t)B*96 + base]
                    + xpP[(size_t)2*B*96 + base] + xpP[(size_t)3*B*96 + base];
    }
    __syncthreads();
    if (t < 64){
        int rx = t >> 4, q = t & 15;
        rowSP[rx][q] = packh2(rowS[rx][2*q], rowS[rx][2*q+1]);
    }
    __syncthreads();

    if (t < 512){
        int r = (t >> 7) & 3, dl = t & 127;
        int d = g*128 + dl;
        int row = rg*4 + r;
        float dp = dtb[d];
        const uint32* wdt = WdtH + ((size_t)bs << 14) + d;   // [16 r2][1024 d]
        #pragma unroll
        for (int r2 = 0; r2 < 16; r2++)
            dp = dot2h(rowSP[r][r2], wdt[(size_t)r2 << 10], dp);
        float delta = softplusf_(dp);
        float xcv = xcG[(size_t)row*DI + d];
        float dxc = delta*xcv;
        const float4* nap = (const float4*)(negA + ((size_t)bs << 15) + (size_t)d*DS);
        uint4* hb = ((uint4*)hG) + ((size_t)(bs*B + row) << 12) + d;  // [qq][1024]
        float y = 0.f;
        #pragma unroll
        for (int qq = 0; qq < 4; qq++){
            uint4 hu = first ? make_uint4(0u,0u,0u,0u) : hb[qq << 10];
            float4 na0 = nap[2*qq], na1 = nap[2*qq+1];
            int s0 = 8*qq;
            float h0 = loh(hu.x), h1 = hih(hu.x);
            float h2 = loh(hu.y), h3 = hih(hu.y);
            float h4 = loh(hu.z), h5 = hih(hu.z);
            float h6 = loh(hu.w), h7 = hih(hu.w);
            h0 = __expf(delta*na0.x)*h0 + dxc*rowS[r][DR+s0+0];
            h1 = __expf(delta*na0.y)*h1 + dxc*rowS[r][DR+s0+1];
            h2 = __expf(delta*na0.z)*h2 + dxc*rowS[r][DR+s0+2];
            h3 = __expf(delta*na0.w)*h3 + dxc*rowS[r][DR+s0+3];
            h4 = __expf(delta*na1.x)*h4 + dxc*rowS[r][DR+s0+4];
            h5 = __expf(delta*na1.y)*h5 + dxc*rowS[r][DR+s0+5];
            h6 = __expf(delta*na1.z)*h6 + dxc*rowS[r][DR+s0+6];
            h7 = __expf(delta*na1.w)*h7 + dxc*rowS[r][DR+s0+7];
            y += h0*rowS[r][DR+DS+s0+0] + h1*rowS[r][DR+DS+s0+1]
               + h2*rowS[r][DR+DS+s0+2] + h3*rowS[r][DR+DS+s0+3]
               + h4*rowS[r][DR+DS+s0+4] + h5*rowS[r][DR+DS+s0+5]
               + h6*rowS[r][DR+DS+s0+6] + h7*rowS[r][DR+DS+s0+7];
            hu.x = packh2(h0,h1); hu.y = packh2(h2,h3);
            hu.z = packh2(h4,h5); hu.w = packh2(h6,h7);
            hb[qq << 10] = hu;
        }
        y += Dp[d]*xcv;
        yzL[r][dl] = y*szG[(size_t)row*DI + d];
    }
    __syncthreads();
    if (t < 256){
        int r = t >> 6, k2 = t & 63;
        yzP[r][k2] = packh2(yzL[r][2*k2], yzL[r][2*k2+1]);
    }
    __syncthreads();

    // gemm2: thread = (colquad cq of 128, row rr of 4, k2-split ks of 2x32)
    {
        int cq = t & 127, rr = (t >> 7) & 3, ks = t >> 9;
        const uint32* wo = WoH + ((size_t)bs << 18);      // [512 k2][512 c]
        int k2b = g*64 + ks*32;
        const uint4* wp = (const uint4*)(wo + ((size_t)k2b << 9)) + cq;
        const uint32* yr = &yzP[rr][ks*32];
        float b0=0.f,b1=0.f,b2=0.f,b3=0.f;
        #pragma unroll 8
        for (int k2 = 0; k2 < 32; k2++){
            uint4 q = wp[(size_t)k2 << 7];
            uint32 ya = yr[k2];
            b0 = dot2h(ya, q.x, b0);
            b1 = dot2h(ya, q.y, b1);
            b2 = dot2h(ya, q.z, b2);
            b3 = dot2h(ya, q.w, b3);
        }
        *(float4*)&red2[ks][rr][4*cq] = make_float4(b0,b1,b2,b3);
    }
    __syncthreads();
    if (t < 512){
        int r2 = t >> 7, c = t & 127;
        int row2 = rg*4 + r2;
        float4 s0 = *(float4*)&red2[0][r2][4*c];
        float4 s1 = *(float4*)&red2[1][r2][4*c];
        *(float4*)&pP[((size_t)g*B + row2)*DM + 4*c] =
            make_float4(s0.x+s1.x, s0.y+s1.y, s0.z+s1.z, s0.w+s1.w);
    }
}

// head: fold(8 partials), LN, W_head GEMV, outputs, next x, zero partials
__global__ __launch_bounds__(512) void k_head(
    const float* __restrict__ xin, float* __restrict__ xout,
    float* __restrict__ pP,
    const float* __restrict__ lno, const float* __restrict__ Whead,
    const float* __restrict__ logstd, const float* __restrict__ eps,
    const float* __restrict__ Wemb, const float* __restrict__ bemb,
    float* __restrict__ out, int agent)
{
    int b = blockIdx.x, t = threadIdx.x, lane = t & 63, wid = t >> 6;
    __shared__ float ulnL[512];
    __shared__ float redH[512];
    __shared__ float wps[8], wpq[8], ms2[2];
    __shared__ float actv[AD], lpterm[AD];

    float v = xin[(size_t)b*DM + t];
    #pragma unroll
    for (int g = 0; g < 8; g++) v += pP[((size_t)g*B + b)*DM + t];
    float s = v, q = v*v;
    for (int off = 32; off > 0; off >>= 1){
        s += __shfl_down(s, off);
        q += __shfl_down(q, off);
    }
    if (lane == 0){ wps[wid] = s; wpq[wid] = q; }
    __syncthreads();
    if (t == 0){
        float S = 0.f, Q = 0.f;
        #pragma unroll
        for (int w2 = 0; w2 < 8; w2++){ S += wps[w2]; Q += wpq[w2]; }
        float m = S*(1.0f/DM);
        float var = Q*(1.0f/DM) - m*m;
        ms2[0] = m; ms2[1] = rsqrtf(var + 1e-5f);
    }
    __syncthreads();
    ulnL[t] = (v - ms2[0])*ms2[1]*lno[t];
    __syncthreads();
    {
        int ks = t >> 4, j = t & 15;
        float acc = 0.f;
        int k0 = ks*16;
        #pragma unroll
        for (int k = k0; k < k0 + 16; k++)
            acc += ulnL[k]*Whead[k*AD + j];
        redH[t] = acc;
    }
    __syncthreads();
    if (t < AD){
        int j = t;
        float mean = 0.f;
        #pragma unroll
        for (int ks = 0; ks < 32; ks++) mean += redH[ks*16 + j];
        float stdj = softplusf_(logstd[j]);
        float e = eps[((size_t)b*NA + agent)*AD + j];
        float raw = mean + stdj*e;
        float act = tanhf(raw);
        out[((size_t)b*NA + agent)*AD + j] = act;                                    // acts
        out[(size_t)NA*B*AD + (size_t)B*NA + ((size_t)b*NA + agent)*AD + j] = raw;   // raws
        actv[j] = act;
        lpterm[j] = -0.5f*e*e - logf(stdj)
                    - 2.0f*(0.69314718f - raw - softplusf_(-2.0f*raw));
    }
    __syncthreads();
    if (t == 0){
        float lp = 0.f;
        #pragma unroll
        for (int j = 0; j < AD; j++) lp += lpterm[j];
        lp -= 0.5f*AD*1.8378770664f;
        out[(size_t)NA*B*AD + (size_t)b*NA + agent] = lp;                            // logs
    }
    float v2 = bemb[t];
    #pragma unroll
    for (int j = 0; j < AD; j++)
        v2 += actv[j]*Wemb[j*DM + t];
    xout[(size_t)b*DM + t] = v2;
    #pragma unroll
    for (int g = 0; g < 8; g++) pP[((size_t)g*B + b)*DM + t] = 0.f;
}

// ---------------- launch ----------------

extern "C" void kernel_launch(void* const* d_in, const int* in_sizes, int n_in,
                              void* d_out, int out_size, void* d_ws, size_t ws_size,
                              hipStream_t stream)
{
    const float* in[29];
    for (int k = 0; k < 29; k++) in[k] = (const float*)d_in[k];

    // workspace layout (bytes) — identical byte sizes to round 4 (~110 MB of 256 MB)
    char* wsb = (char*)d_ws;
    uint32* W1H  = (uint32*)(wsb + 0);           // 16,777,216  [8][256][2048]
    uint32* WoH  = (uint32*)(wsb + 16777216);    //  8,388,608  [8][512][512]
    uint32* WxH  = (uint32*)(wsb + 25165824);    //  1,572,864  [8][96][512]
    uint32* WdtH = (uint32*)(wsb + 26738688);    //    524,288  [8][16][1024]
    float*  negA = (float*) (wsb + 27262976);    //  1,048,576
    float*  ctx  = (float*) (wsb + 28311552);    //  2,097,152
    float*  xb0  = (float*) (wsb + 30408704);    //    262,144
    float*  xb1  = (float*) (wsb + 30670848);    //    262,144
    float*  xcG  = (float*) (wsb + 30932992);    //    524,288
    float*  szG  = (float*) (wsb + 31457280);    //    524,288
    float*  xpP  = (float*) (wsb + 31981568);    //    262,144 (uses 196,608)
    float*  pP   = (float*) (wsb + 32243712);    //  2,097,152  [8][B][DM]
    uint32* convrU = (uint32*)(wsb + 34340864);  //  8,388,608  f16-pair ring
    uint32* hG   = (uint32*)(wsb + 42729472);    // 67,108,864  [bs][row][qq][d] uint4 f16

    float* out = (float*)d_out;
    float* xb[2] = {xb0, xb1};

    k_negA<<<dim3(1024),  256, 0, stream>>>(in[17], in[26], negA);
    k_ctx <<<dim3(B*NA),  256, 0, stream>>>(in[0], in[1], in[5], ctx);
    k_w1h <<<dim3(16384), 256, 0, stream>>>(in[11], in[20], W1H);
    k_woh <<<dim3(8192),  256, 0, stream>>>(in[19], in[28], WoH);
    k_wxh <<<dim3(1536),  256, 0, stream>>>(in[14], in[23], WxH);
    k_wdth<<<dim3(512),   256, 0, stream>>>(in[15], in[24], WdtH);
    k_init<<<dim3(2048),  256, 0, stream>>>(in[4], xb0, pP);

    int cur = 0;
    for (int i = 0; i < NA; i++){
        for (int nb = 0; nb < NB; nb++){
            for (int st = 0; st < 2; st++){
                int bs = nb*2 + st;
                int base = st ? 20 : 11;
                const float* cw   = in[base+1] + (size_t)nb*DC*DI;
                const float* cb   = in[base+2] + (size_t)nb*DI;
                const float* dtbp = in[base+5] + (size_t)nb*DI;
                const float* Dpp  = in[base+7] + (size_t)nb*DI;
                const float* lns  = (st ? in[7] : in[6]) + (size_t)nb*DM;

                k_step1<<<dim3(256), 1024, 0, stream>>>(xb[cur], pP, xb[cur^1],
                        lns, ctx, W1H, WxH, cw, cb, convrU, xcG, szG, xpP, i, st, bs);
                cur ^= 1;
                k_step2<<<dim3(256), 1024, 0, stream>>>(xcG, szG, xpP, WdtH,
                        dtbp, Dpp, negA, WoH, hG, pP, (i==0) ? 1 : 0, bs);
            }
        }
        k_head<<<dim3(B), 512, 0, stream>>>(xb[cur], xb[cur^1], pP,
                in[8], in[9], in[10], in[2], in[3], in[4], out, i);
        cur ^= 1;
    }
}

// Round 7
// 1944.669 us; speedup vs baseline: 3.3572x; 1.1977x over previous
//
#include <hip/hip_runtime.h>
#include <hip/hip_bf16.h>

#define B   128
#define NA  8
#define AD  16
#define DM  512
#define DI  1024
#define DS  32
#define DC  4
#define DR  32
#define NB  4
#define OD  128

typedef unsigned int uint32;
typedef _Float16 h2f __attribute__((ext_vector_type(2)));

__device__ __forceinline__ float sigmoidf_(float x){ return 1.0f/(1.0f+__expf(-x)); }
__device__ __forceinline__ float softplusf_(float x){ return fmaxf(x,0.0f)+log1pf(__expf(-fabsf(x))); }

// f16 pair helpers: one uint32 = half2 (lo = first, hi = second)
__device__ __forceinline__ float dot2h(uint32 a, uint32 b, float c){
    union { uint32 u; h2f h; } ua, ub;
    ua.u = a; ub.u = b;
#if __has_builtin(__builtin_amdgcn_fdot2)
    return __builtin_amdgcn_fdot2(ua.h, ub.h, c, false);
#else
    return c + (float)ua.h.x*(float)ub.h.x + (float)ua.h.y*(float)ub.h.y;
#endif
}
__device__ __forceinline__ uint32 packh2(float a, float b){
    union { uint32 u; h2f h; } w;
    w.h.x = (_Float16)a; w.h.y = (_Float16)b;
    return w.u;
}
__device__ __forceinline__ float loh(uint32 u){
    union { uint32 uu; h2f h; } w; w.uu = u; return (float)w.h.x;
}
__device__ __forceinline__ float hih(uint32 u){
    union { uint32 uu; h2f h; } w; w.uu = u; return (float)w.h.y;
}

// ---------------- init / conversion kernels ----------------

__global__ __launch_bounds__(256) void k_negA(const float* __restrict__ Als,
    const float* __restrict__ Alc, float* __restrict__ negA)
{
    int idx = blockIdx.x*256 + threadIdx.x;   // < 2*NB*DI*DS = 262144
    int bs = idx >> 15;
    int r  = idx & 32767;
    int nb = bs >> 1, st = bs & 1;
    const float* src = (st ? Alc : Als) + (size_t)nb*DI*DS + r;
    negA[idx] = -__expf(*src);
}

__global__ __launch_bounds__(256) void k_ctx(const float* __restrict__ obs_rep,
    const float* __restrict__ obs, const float* __restrict__ Wobs,
    float* __restrict__ ctx)
{
    int ib = blockIdx.x;          // < B*8
    int b = ib >> 3, i = ib & 7;
    __shared__ float orow[OD];
    int tid = threadIdx.x;
    if (tid < OD) orow[tid] = obs[(size_t)(b*NA+i)*OD + tid];
    __syncthreads();
    for (int m = tid; m < DM; m += 256){
        float acc = obs_rep[(size_t)(b*NA+i)*DM + m];
        for (int o = 0; o < OD; o++)
            acc += orow[o]*Wobs[o*DM + m];
        ctx[(size_t)(i*B + b)*DM + m] = acc;
    }
}

// W1H[bs][k2][c] uint32 = half2(W[2k2][c], W[2k2+1][c]); [8][256][2048]
__global__ __launch_bounds__(256) void k_w1h(const float* __restrict__ Ws,
    const float* __restrict__ Wc, uint32* __restrict__ W1H)
{
    int idx = blockIdx.x*256 + threadIdx.x;   // < 8*524288
    int bs = idx >> 19;
    int r  = idx & 524287;
    int k2 = r >> 11, c = r & 2047;
    int nb = bs >> 1, st = bs & 1;
    const float* src = (st ? Wc : Ws) + (size_t)nb*1048576 + (size_t)(2*k2)*2048 + c;
    W1H[idx] = packh2(src[0], src[2048]);
}

// WoH[bs][k2][c] uint32 = half2(Wo[2k2][c], Wo[2k2+1][c]); [8][512][512]
__global__ __launch_bounds__(256) void k_woh(const float* __restrict__ Ws,
    const float* __restrict__ Wc, uint32* __restrict__ WoH)
{
    int idx = blockIdx.x*256 + threadIdx.x;   // < 8*262144
    int bs = idx >> 18;
    int r  = idx & 262143;
    int k2 = r >> 9, c = r & 511;
    int nb = bs >> 1, st = bs & 1;
    const float* src = (st ? Wc : Ws) + (size_t)nb*DI*DM + (size_t)(2*k2)*DM + c;
    WoH[idx] = packh2(src[0], src[DM]);
}

// WxH[bs][j][k2] uint32 = half2(X[2k2][j], X[2k2+1][j]); [8][96][512]
__global__ __launch_bounds__(256) void k_wxh(const float* __restrict__ Ws,
    const float* __restrict__ Wc, uint32* __restrict__ WxH)
{
    int idx = blockIdx.x*256 + threadIdx.x;   // < 8*49152
    int bs = idx / 49152;
    int r  = idx % 49152;
    int j  = r >> 9, k2 = r & 511;
    int nb = bs >> 1, st = bs & 1;
    const float* src = (st ? Wc : Ws) + (size_t)nb*DI*96 + (size_t)(2*k2)*96 + j;
    WxH[idx] = packh2(src[0], src[96]);
}

// WdtH[bs][r2][d] uint32 = half2(Wd[2r2][d], Wd[2r2+1][d]); [8][16][1024]
__global__ __launch_bounds__(256) void k_wdth(const float* __restrict__ Ws,
    const float* __restrict__ Wc, uint32* __restrict__ WdtH)
{
    int idx = blockIdx.x*256 + threadIdx.x;   // < 8*16384
    int bs = idx >> 14;
    int r  = idx & 16383;
    int r2 = r >> 10, d = r & 1023;
    int nb = bs >> 1, st = bs & 1;
    const float* src = (st ? Wc : Ws) + (size_t)nb*DR*DI + (size_t)(2*r2)*DI + d;
    WdtH[idx] = packh2(src[0], src[DI]);
}

// x0 = bemb broadcast; zero 8 partial buffers pP[8][B][DM]
__global__ __launch_bounds__(256) void k_init(const float* __restrict__ bemb,
    float* __restrict__ xb0, float* __restrict__ pP)
{
    int idx = blockIdx.x*256 + threadIdx.x;   // < 8*B*DM = 524288
    if (idx < B*DM) xb0[idx] = bemb[idx & (DM-1)];
    pP[idx] = 0.f;
}

// ---------------- per-step kernels ----------------

struct SP {
    const uint32 *W1H, *WoH, *WxH, *WdtH;
    const float *negA, *ctxG;
    const float *cw_s, *cb_s, *dtb_s, *D_s;
    const float *cw_c, *cb_c, *dtb_c, *D_c;
    const float *ln1, *ln2;
    float *xcG, *szG, *xpP, *pP;
    uint32 *convrU, *hG;
};

// grid 256 = 32 rowgroups (R=4 rows) x 8 colgroups, 1024 threads.
// gemm1 weights: one thread loads a uint4 once and applies it to all 4 rows
// (16 dot2 / 16B load).
__global__ __launch_bounds__(1024) void k_step1(SP P, const float* __restrict__ xin,
    float* __restrict__ xout, int i, int bs)
{
    int rg = blockIdx.x >> 3, cg = blockIdx.x & 7;
    int t = threadIdx.x;
    int st = bs & 1, nb = bs >> 1;
    const float* lns = (st ? P.ln2 : P.ln1) + (size_t)nb*DM;
    const float* cw  = (st ? P.cw_c : P.cw_s) + (size_t)nb*DC*DI;
    const float* cb  = (st ? P.cb_c : P.cb_s) + (size_t)nb*DI;

    __shared__ uint32 ulnP[4][256];
    __shared__ float red1[16][4][256];   // 64 KB
    __shared__ float xzL[4][256];
    __shared__ uint32 xcP[4][128];
    __shared__ float wred[4][2][2];
    __shared__ float ms2[4][2];

    // ---- fold x + sum(pP) (t<512: row r of 4, 4 consecutive cols) ----
    int r = (t >> 7) & 3, cq = t & 127;
    float4 v4 = make_float4(0.f,0.f,0.f,0.f);
    if (t < 512){
        int row = rg*4 + r;
        v4 = *(const float4*)&xin[(size_t)row*DM + cq*4];
        #pragma unroll
        for (int gg = 0; gg < 8; gg++){
            float4 q4 = *(const float4*)&P.pP[((size_t)gg*B + row)*DM + cq*4];
            v4.x += q4.x; v4.y += q4.y; v4.z += q4.z; v4.w += q4.w;
        }
        if (cg == 0) *(float4*)&xout[(size_t)row*DM + cq*4] = v4;
        float sv = v4.x+v4.y+v4.z+v4.w;
        float qv = v4.x*v4.x+v4.y*v4.y+v4.z*v4.z+v4.w*v4.w;
        #pragma unroll
        for (int off = 32; off > 0; off >>= 1){
            sv += __shfl_down(sv, off);
            qv += __shfl_down(qv, off);
        }
        int lane = t & 63, wid = t >> 6;
        if (lane == 0){ wred[wid>>1][wid&1][0] = sv; wred[wid>>1][wid&1][1] = qv; }
    }
    __syncthreads();
    if (t < 4){
        float S = wred[t][0][0] + wred[t][1][0];
        float Q = wred[t][0][1] + wred[t][1][1];
        float m = S*(1.0f/DM);
        float var = Q*(1.0f/DM) - m*m;
        ms2[t][0] = m; ms2[t][1] = rsqrtf(var + 1e-5f);
    }
    __syncthreads();

    // ---- LN -> packed f16 pairs ----
    if (t < 512){
        int row = rg*4 + r;
        float m = ms2[r][0], rs = ms2[r][1];
        float4 l4 = *(const float4*)&lns[cq*4];
        float u0 = (v4.x - m)*rs*l4.x;
        float u1 = (v4.y - m)*rs*l4.y;
        float u2 = (v4.z - m)*rs*l4.z;
        float u3 = (v4.w - m)*rs*l4.w;
        if (st){
            float4 c4 = *(const float4*)&P.ctxG[((size_t)i*B + row)*DM + cq*4];
            u0 += c4.x; u1 += c4.y; u2 += c4.z; u3 += c4.w;
        }
        ulnP[r][2*cq]   = packh2(u0, u1);
        ulnP[r][2*cq+1] = packh2(u2, u3);
    }
    __syncthreads();

    // ---- gemm1: thread = (colquad cp of 64, k2-chunk kg of 16x16); 4 rows each ----
    {
        int cp = t & 63, kg = t >> 6;
        const uint32* w1 = P.W1H + ((size_t)bs << 19);     // [256 k2][2048 c]
        int k2b = kg*16;
        const uint4* wp = (const uint4*)(w1 + ((size_t)k2b << 11)) + (cg*64 + cp);
        float a[4][4] = {};
        #pragma unroll 4
        for (int k2i = 0; k2i < 16; k2i++){
            uint4 q = wp[(size_t)k2i << 9];
            int k2 = k2b + k2i;
            uint32 u0 = ulnP[0][k2], u1 = ulnP[1][k2];
            uint32 u2 = ulnP[2][k2], u3 = ulnP[3][k2];
            a[0][0]=dot2h(u0,q.x,a[0][0]); a[0][1]=dot2h(u0,q.y,a[0][1]);
            a[0][2]=dot2h(u0,q.z,a[0][2]); a[0][3]=dot2h(u0,q.w,a[0][3]);
            a[1][0]=dot2h(u1,q.x,a[1][0]); a[1][1]=dot2h(u1,q.y,a[1][1]);
            a[1][2]=dot2h(u1,q.z,a[1][2]); a[1][3]=dot2h(u1,q.w,a[1][3]);
            a[2][0]=dot2h(u2,q.x,a[2][0]); a[2][1]=dot2h(u2,q.y,a[2][1]);
            a[2][2]=dot2h(u2,q.z,a[2][2]); a[2][3]=dot2h(u2,q.w,a[2][3]);
            a[3][0]=dot2h(u3,q.x,a[3][0]); a[3][1]=dot2h(u3,q.y,a[3][1]);
            a[3][2]=dot2h(u3,q.z,a[3][2]); a[3][3]=dot2h(u3,q.w,a[3][3]);
        }
        #pragma unroll
        for (int rr = 0; rr < 4; rr++)
            *(float4*)&red1[kg][rr][4*cp] = make_float4(a[rr][0],a[rr][1],a[rr][2],a[rr][3]);
    }
    __syncthreads();
    {
        int r2 = t >> 8, c = t & 255;
        float sacc = red1[0][r2][c];
        #pragma unroll
        for (int gk = 1; gk < 16; gk++) sacc += red1[gk][r2][c];
        xzL[r2][c] = sacc;
    }
    __syncthreads();

    if (cg < 4){
        // ---- conv ring + silu -> xc (t<512) ----
        if (t < 512){
            int r3 = r, pi = cq;
            int row3 = rg*4 + r3;
            int d0 = cg*256 + 2*pi;
            float xz0 = xzL[r3][2*pi], xz1 = xzL[r3][2*pi+1];
            uint32* ring = P.convrU + ((size_t)bs << 18);   // [4][128][512] f16 pairs
            size_t rb = (size_t)row3*512 + (d0>>1);
            ring[((size_t)(i&3))*65536 + rb] = packh2(xz0, xz1);
            float s0 = cb[d0]   + cw[3*DI + d0]  *xz0;
            float s1 = cb[d0+1] + cw[3*DI + d0+1]*xz1;
            if (i >= 1){ uint32 uu = ring[((size_t)((i-1)&3))*65536 + rb];
                s0 += cw[2*DI + d0]*loh(uu); s1 += cw[2*DI + d0+1]*hih(uu); }
            if (i >= 2){ uint32 uu = ring[((size_t)((i-2)&3))*65536 + rb];
                s0 += cw[1*DI + d0]*loh(uu); s1 += cw[1*DI + d0+1]*hih(uu); }
            if (i >= 3){ uint32 uu = ring[((size_t)((i-3)&3))*65536 + rb];
                s0 += cw[0*DI + d0]*loh(uu); s1 += cw[0*DI + d0+1]*hih(uu); }
            float xc0 = s0*sigmoidf_(s0), xc1 = s1*sigmoidf_(s1);
            P.xcG[(size_t)row3*DI + d0]   = xc0;
            P.xcG[(size_t)row3*DI + d0+1] = xc1;
            xcP[r3][pi] = packh2(xc0, xc1);
        }
        __syncthreads();
        // ---- xproj partial over this 256-k slice (128 k2, dot2) ----
        if (t < 384){
            int rx = t/96, j = t - rx*96;
            const uint4* wx = (const uint4*)(P.WxH + (size_t)bs*49152
                                             + ((size_t)j << 9) + (cg << 7));
            const uint32* xr = xcP[rx];
            float acc = 0.f;
            #pragma unroll 8
            for (int ii = 0; ii < 32; ii++){
                uint4 q = wx[ii];
                acc = dot2h(xr[4*ii+0], q.x, acc);
                acc = dot2h(xr[4*ii+1], q.y, acc);
                acc = dot2h(xr[4*ii+2], q.z, acc);
                acc = dot2h(xr[4*ii+3], q.w, acc);
            }
            P.xpP[((size_t)cg*B + rg*4 + rx)*96 + j] = acc;
        }
    } else {
        // ---- z path: sz ----
        int r2 = t >> 8, c = t & 255;
        int row2 = rg*4 + r2;
        int d = (cg-4)*256 + c;
        float xz = xzL[r2][c];
        P.szG[(size_t)row2*DI + d] = xz*sigmoidf_(xz);
    }
}

// step2: rowS fold, dt (dot2), scan + y, gemm2 (thread loads weight uint4 once,
// applies to 4 rows: 8 loads / 128 dot2) -> pP[g]
__global__ __launch_bounds__(1024) void k_step2(SP P, int i, int bs)
{
    int rg = blockIdx.x >> 3, g = blockIdx.x & 7;
    int t = threadIdx.x;
    int st = bs & 1, nb = bs >> 1;
    const float* dtbp = (st ? P.dtb_c : P.dtb_s) + (size_t)nb*DI;
    const float* Dpp  = (st ? P.D_c   : P.D_s  ) + (size_t)nb*DI;
    const int first = (i == 0);

    __shared__ float rowS[4][96];
    __shared__ uint32 rowSP[4][16];
    __shared__ float yzL[4][128];
    __shared__ uint32 yzP[4][64];
    __shared__ float red2[8][4][624];   // padded cols: ~80 KB -> 1 block/CU

    if (t < 384){
        int rx = t/96, j = t - rx*96;
        int row0 = rg*4 + rx;
        size_t base = (size_t)row0*96 + j;
        rowS[rx][j] = P.xpP[base] + P.xpP[(size_t)B*96 + base]
                    + P.xpP[(size_t)2*B*96 + base] + P.xpP[(size_t)3*B*96 + base];
    }
    __syncthreads();
    if (t < 64){
        int rx = t >> 4, q = t & 15;
        rowSP[rx][q] = packh2(rowS[rx][2*q], rowS[rx][2*q+1]);
    }
    __syncthreads();

    if (t < 512){
        int r = t >> 7, dl = t & 127;
        int d = g*128 + dl;
        int row = rg*4 + r;
        float dp = dtbp[d];
        const uint32* wdt = P.WdtH + ((size_t)bs << 14) + d;   // [16 r2][1024 d]
        #pragma unroll
        for (int r2 = 0; r2 < 16; r2++)
            dp = dot2h(rowSP[r][r2], wdt[(size_t)r2 << 10], dp);
        float delta = softplusf_(dp);
        float xcv = P.xcG[(size_t)row*DI + d];
        float dxc = delta*xcv;
        const float4* nap = (const float4*)(P.negA + ((size_t)bs << 15) + (size_t)d*DS);
        uint4* hb = ((uint4*)P.hG) + ((size_t)(bs*B + row) << 12) + d;  // [qq][1024]
        float y = 0.f;
        #pragma unroll
        for (int qq = 0; qq < 4; qq++){
            uint4 hu = first ? make_uint4(0u,0u,0u,0u) : hb[qq << 10];
            float4 na0 = nap[2*qq], na1 = nap[2*qq+1];
            int s0 = 8*qq;
            float h0 = loh(hu.x), h1 = hih(hu.x);
            float h2 = loh(hu.y), h3 = hih(hu.y);
            float h4 = loh(hu.z), h5 = hih(hu.z);
            float h6 = loh(hu.w), h7 = hih(hu.w);
            h0 = __expf(delta*na0.x)*h0 + dxc*rowS[r][DR+s0+0];
            h1 = __expf(delta*na0.y)*h1 + dxc*rowS[r][DR+s0+1];
            h2 = __expf(delta*na0.z)*h2 + dxc*rowS[r][DR+s0+2];
            h3 = __expf(delta*na0.w)*h3 + dxc*rowS[r][DR+s0+3];
            h4 = __expf(delta*na1.x)*h4 + dxc*rowS[r][DR+s0+4];
            h5 = __expf(delta*na1.y)*h5 + dxc*rowS[r][DR+s0+5];
            h6 = __expf(delta*na1.z)*h6 + dxc*rowS[r][DR+s0+6];
            h7 = __expf(delta*na1.w)*h7 + dxc*rowS[r][DR+s0+7];
            y += h0*rowS[r][DR+DS+s0+0] + h1*rowS[r][DR+DS+s0+1]
               + h2*rowS[r][DR+DS+s0+2] + h3*rowS[r][DR+DS+s0+3]
               + h4*rowS[r][DR+DS+s0+4] + h5*rowS[r][DR+DS+s0+5]
               + h6*rowS[r][DR+DS+s0+6] + h7*rowS[r][DR+DS+s0+7];
            hu.x = packh2(h0,h1); hu.y = packh2(h2,h3);
            hu.z = packh2(h4,h5); hu.w = packh2(h6,h7);
            hb[qq << 10] = hu;
        }
        y += Dpp[d]*xcv;
        yzL[r][dl] = y*P.szG[(size_t)row*DI + d];
    }
    __syncthreads();
    if (t < 256){
        int r = t >> 6, k2 = t & 63;
        yzP[r][k2] = packh2(yzL[r][2*k2], yzL[r][2*k2+1]);
    }
    __syncthreads();

    // gemm2: thread = (colquad cq of 128, k2-chunk kg of 8x8); 4 rows each
    {
        int cq = t & 127, kg = t >> 7;
        const uint32* wo = P.WoH + ((size_t)bs << 18);      // [512 k2][512 c]
        int k2b = g*64 + kg*8;
        const uint4* wp = (const uint4*)(wo + ((size_t)k2b << 9)) + cq;
        float a[4][4] = {};
        #pragma unroll
        for (int k2i = 0; k2i < 8; k2i++){
            uint4 q = wp[(size_t)k2i << 7];
            int k2l = kg*8 + k2i;
            uint32 y0 = yzP[0][k2l], y1 = yzP[1][k2l];
            uint32 y2 = yzP[2][k2l], y3 = yzP[3][k2l];
            a[0][0]=dot2h(y0,q.x,a[0][0]); a[0][1]=dot2h(y0,q.y,a[0][1]);
            a[0][2]=dot2h(y0,q.z,a[0][2]); a[0][3]=dot2h(y0,q.w,a[0][3]);
            a[1][0]=dot2h(y1,q.x,a[1][0]); a[1][1]=dot2h(y1,q.y,a[1][1]);
            a[1][2]=dot2h(y1,q.z,a[1][2]); a[1][3]=dot2h(y1,q.w,a[1][3]);
            a[2][0]=dot2h(y2,q.x,a[2][0]); a[2][1]=dot2h(y2,q.y,a[2][1]);
            a[2][2]=dot2h(y2,q.z,a[2][2]); a[2][3]=dot2h(y2,q.w,a[2][3]);
            a[3][0]=dot2h(y3,q.x,a[3][0]); a[3][1]=dot2h(y3,q.y,a[3][1]);
            a[3][2]=dot2h(y3,q.z,a[3][2]); a[3][3]=dot2h(y3,q.w,a[3][3]);
        }
        #pragma unroll
        for (int rr = 0; rr < 4; rr++)
            *(float4*)&red2[kg][rr][4*cq] = make_float4(a[rr][0],a[rr][1],a[rr][2],a[rr][3]);
    }
    __syncthreads();
    if (t < 512){
        int r2 = t >> 7, c4 = t & 127;
        float4 s = *(float4*)&red2[0][r2][4*c4];
        #pragma unroll
        for (int kg = 1; kg < 8; kg++){
            float4 q = *(float4*)&red2[kg][r2][4*c4];
            s.x += q.x; s.y += q.y; s.z += q.z; s.w += q.w;
        }
        *(float4*)&P.pP[((size_t)g*B + rg*4 + r2)*DM + 4*c4] = s;
    }
}

// per-agent head: fold(8 partials), LN, W_head GEMV, outputs, next x, zero partials
__global__ __launch_bounds__(512) void k_head(
    const float* __restrict__ xin, float* __restrict__ xout,
    float* __restrict__ pP,
    const float* __restrict__ lno, const float* __restrict__ Whead,
    const float* __restrict__ logstd, const float* __restrict__ eps,
    const float* __restrict__ Wemb, const float* __restrict__ bemb,
    float* __restrict__ out, int agent)
{
    int b = blockIdx.x, t = threadIdx.x, lane = t & 63, wid = t >> 6;
    __shared__ float ulnL[512];
    __shared__ float redH[512];
    __shared__ float wps[8], wpq[8], ms2[2];
    __shared__ float actv[AD], lpterm[AD];

    float v = xin[(size_t)b*DM + t];
    #pragma unroll
    for (int g = 0; g < 8; g++) v += pP[((size_t)g*B + b)*DM + t];
    float s = v, q = v*v;
    for (int off = 32; off > 0; off >>= 1){
        s += __shfl_down(s, off);
        q += __shfl_down(q, off);
    }
    if (lane == 0){ wps[wid] = s; wpq[wid] = q; }
    __syncthreads();
    if (t == 0){
        float S = 0.f, Q = 0.f;
        #pragma unroll
        for (int w2 = 0; w2 < 8; w2++){ S += wps[w2]; Q += wpq[w2]; }
        float m = S*(1.0f/DM);
        float var = Q*(1.0f/DM) - m*m;
        ms2[0] = m; ms2[1] = rsqrtf(var + 1e-5f);
    }
    __syncthreads();
    ulnL[t] = (v - ms2[0])*ms2[1]*lno[t];
    __syncthreads();
    {
        int ks = t >> 4, j = t & 15;
        float acc = 0.f;
        int k0 = ks*16;
        #pragma unroll
        for (int k = k0; k < k0 + 16; k++)
            acc += ulnL[k]*Whead[k*AD + j];
        redH[t] = acc;
    }
    __syncthreads();
    if (t < AD){
        int j = t;
        float mean = 0.f;
        #pragma unroll
        for (int ks = 0; ks < 32; ks++) mean += redH[ks*16 + j];
        float stdj = softplusf_(logstd[j]);
        float e = eps[((size_t)b*NA + agent)*AD + j];
        float raw = mean + stdj*e;
        float act = tanhf(raw);
        out[((size_t)b*NA + agent)*AD + j] = act;                                    // acts
        out[(size_t)NA*B*AD + (size_t)B*NA + ((size_t)b*NA + agent)*AD + j] = raw;   // raws
        actv[j] = act;
        lpterm[j] = -0.5f*e*e - logf(stdj)
                    - 2.0f*(0.69314718f - raw - softplusf_(-2.0f*raw));
    }
    __syncthreads();
    if (t == 0){
        float lp = 0.f;
        #pragma unroll
        for (int j = 0; j < AD; j++) lp += lpterm[j];
        lp -= 0.5f*AD*1.8378770664f;
        out[(size_t)NA*B*AD + (size_t)b*NA + agent] = lp;                            // logs
    }
    float v2 = bemb[t];
    #pragma unroll
    for (int j = 0; j < AD; j++)
        v2 += actv[j]*Wemb[j*DM + t];
    xout[(size_t)b*DM + t] = v2;
    #pragma unroll
    for (int g = 0; g < 8; g++) pP[((size_t)g*B + b)*DM + t] = 0.f;
}

// ---------------- launch ----------------

extern "C" void kernel_launch(void* const* d_in, const int* in_sizes, int n_in,
                              void* d_out, int out_size, void* d_ws, size_t ws_size,
                              hipStream_t stream)
{
    const float* in[29];
    for (int k = 0; k < 29; k++) in[k] = (const float*)d_in[k];

    // workspace layout (bytes) — same as round 5 (~110 MB of 256 MB)
    char* wsb = (char*)d_ws;
    uint32* W1H  = (uint32*)(wsb + 0);           // 16,777,216  [8][256][2048]
    uint32* WoH  = (uint32*)(wsb + 16777216);    //  8,388,608  [8][512][512]
    uint32* WxH  = (uint32*)(wsb + 25165824);    //  1,572,864  [8][96][512]
    uint32* WdtH = (uint32*)(wsb + 26738688);    //    524,288  [8][16][1024]
    float*  negA = (float*) (wsb + 27262976);    //  1,048,576
    float*  ctx  = (float*) (wsb + 28311552);    //  2,097,152
    float*  xb0  = (float*) (wsb + 30408704);    //    262,144
    float*  xb1  = (float*) (wsb + 30670848);    //    262,144
    float*  xcG  = (float*) (wsb + 30932992);    //    524,288
    float*  szG  = (float*) (wsb + 31457280);    //    524,288
    float*  xpP  = (float*) (wsb + 31981568);    //    262,144 (uses 196,608)
    float*  pP   = (float*) (wsb + 32243712);    //  2,097,152  [8][B][DM]
    uint32* convrU = (uint32*)(wsb + 34340864);  //  8,388,608  f16-pair ring
    uint32* hG   = (uint32*)(wsb + 42729472);    // 67,108,864  [bs][row][qq][d] f16 uint4

    float* out = (float*)d_out;
    float* xb[2] = {xb0, xb1};

    k_negA<<<dim3(1024),  256, 0, stream>>>(in[17], in[26], negA);
    k_ctx <<<dim3(B*NA),  256, 0, stream>>>(in[0], in[1], in[5], ctx);
    k_w1h <<<dim3(16384), 256, 0, stream>>>(in[11], in[20], W1H);
    k_woh <<<dim3(8192),  256, 0, stream>>>(in[19], in[28], WoH);
    k_wxh <<<dim3(1536),  256, 0, stream>>>(in[14], in[23], WxH);
    k_wdth<<<dim3(512),   256, 0, stream>>>(in[15], in[24], WdtH);
    k_init<<<dim3(2048),  256, 0, stream>>>(in[4], xb0, pP);

    SP P;
    P.W1H = W1H; P.WoH = WoH; P.WxH = WxH; P.WdtH = WdtH;
    P.negA = negA; P.ctxG = ctx;
    P.cw_s = in[12]; P.cb_s = in[13]; P.dtb_s = in[16]; P.D_s = in[18];
    P.cw_c = in[21]; P.cb_c = in[22]; P.dtb_c = in[25]; P.D_c = in[27];
    P.ln1 = in[6]; P.ln2 = in[7];
    P.xcG = xcG; P.szG = szG; P.xpP = xpP; P.pP = pP;
    P.convrU = convrU; P.hG = hG;

    int cur = 0;
    for (int i = 0; i < NA; i++){
        for (int bs = 0; bs < 8; bs++){
            k_step1<<<dim3(256), 1024, 0, stream>>>(P, xb[cur], xb[cur^1], i, bs);
            cur ^= 1;
            k_step2<<<dim3(256), 1024, 0, stream>>>(P, i, bs);
        }
        k_head<<<dim3(B), 512, 0, stream>>>(xb[cur], xb[cur^1], pP,
                in[8], in[9], in[10], in[2], in[3], in[4], out, i);
        cur ^= 1;
    }
}